// Round 3
// baseline (5528.409 us; speedup 1.0000x reference)
//
#include <hip/hip_runtime.h>
#include <hip/hip_bf16.h>
#include <math.h>

// Problem constants
#define Bv   4
#define LQv  1024
#define Cv   256
#define Hv   8
#define Lv   4
#define Pv   4
#define DFFv 1024
#define DHv  32
#define LSRCv 21760   // 128*128 + 64*64 + 32*32 + 16*16

// ---------------------------------------------------------------------------
// elementwise add: out = a + b   (float4 vectorized)
__global__ __launch_bounds__(256) void add_kernel(const float* __restrict__ a,
                                                  const float* __restrict__ b,
                                                  float* __restrict__ out, int n4) {
    int i = blockIdx.x * blockDim.x + threadIdx.x;
    if (i < n4) {
        float4 av = ((const float4*)a)[i];
        float4 bv = ((const float4*)b)[i];
        float4 o;
        o.x = av.x + bv.x; o.y = av.y + bv.y; o.z = av.z + bv.z; o.w = av.w + bv.w;
        ((float4*)out)[i] = o;
    }
}

// ---------------------------------------------------------------------------
// C[M,N] = A[M,K] @ W[N,K]^T + bias[N], optional relu.
#define BM 64
#define BN 64
#define BKt 16
__global__ __launch_bounds__(256) void gemm_bias(const float* __restrict__ A,
                                                 const float* __restrict__ W,
                                                 const float* __restrict__ bias,
                                                 float* __restrict__ Cmat,
                                                 int M, int N, int K, int relu) {
    __shared__ float As[BKt][BM];
    __shared__ float Bs[BKt][BN];
    const int bm = blockIdx.y * BM;
    const int bn = blockIdx.x * BN;
    const int tid = threadIdx.x;
    const int tr = (tid >> 4) << 2;   // row offset 0..60
    const int tc = (tid & 15) << 2;   // col offset 0..60
    float acc[4][4] = {};

    const int lrow = tid >> 2;          // 0..63
    const int lc4  = (tid & 3) << 2;    // 0,4,8,12
    const float* Aptr = A + (size_t)(bm + lrow) * K + lc4;
    const float* Wptr = W + (size_t)(bn + lrow) * K + lc4;

    for (int k0 = 0; k0 < K; k0 += BKt) {
        float4 a4 = *(const float4*)(Aptr + k0);
        float4 w4 = *(const float4*)(Wptr + k0);
        As[lc4 + 0][lrow] = a4.x; As[lc4 + 1][lrow] = a4.y;
        As[lc4 + 2][lrow] = a4.z; As[lc4 + 3][lrow] = a4.w;
        Bs[lc4 + 0][lrow] = w4.x; Bs[lc4 + 1][lrow] = w4.y;
        Bs[lc4 + 2][lrow] = w4.z; Bs[lc4 + 3][lrow] = w4.w;
        __syncthreads();
#pragma unroll
        for (int kk = 0; kk < BKt; ++kk) {
            float a0 = As[kk][tr + 0], a1 = As[kk][tr + 1];
            float a2 = As[kk][tr + 2], a3 = As[kk][tr + 3];
            float b0 = Bs[kk][tc + 0], b1 = Bs[kk][tc + 1];
            float b2 = Bs[kk][tc + 2], b3 = Bs[kk][tc + 3];
            acc[0][0] = fmaf(a0, b0, acc[0][0]); acc[0][1] = fmaf(a0, b1, acc[0][1]);
            acc[0][2] = fmaf(a0, b2, acc[0][2]); acc[0][3] = fmaf(a0, b3, acc[0][3]);
            acc[1][0] = fmaf(a1, b0, acc[1][0]); acc[1][1] = fmaf(a1, b1, acc[1][1]);
            acc[1][2] = fmaf(a1, b2, acc[1][2]); acc[1][3] = fmaf(a1, b3, acc[1][3]);
            acc[2][0] = fmaf(a2, b0, acc[2][0]); acc[2][1] = fmaf(a2, b1, acc[2][1]);
            acc[2][2] = fmaf(a2, b2, acc[2][2]); acc[2][3] = fmaf(a2, b3, acc[2][3]);
            acc[3][0] = fmaf(a3, b0, acc[3][0]); acc[3][1] = fmaf(a3, b1, acc[3][1]);
            acc[3][2] = fmaf(a3, b2, acc[3][2]); acc[3][3] = fmaf(a3, b3, acc[3][3]);
        }
        __syncthreads();
    }
#pragma unroll
    for (int i = 0; i < 4; ++i) {
#pragma unroll
        for (int j = 0; j < 4; ++j) {
            float v = acc[i][j] + bias[bn + tc + j];
            if (relu) v = fmaxf(v, 0.f);
            Cmat[(size_t)(bm + tr + i) * N + bn + tc + j] = v;
        }
    }
}

// ---------------------------------------------------------------------------
// Flash-style self-attention, key-split across 4 waves, LDS-staged K/V with
// per-wave double-buffered prefetch (no barriers in the hot loop).
// grid: (LQ/64, H, B), block: 256 (4 waves). lane = query, wave = 256-key range.
__global__ __launch_bounds__(256) void attn_kernel(const float* __restrict__ Q,
                                                   const float* __restrict__ Kb,
                                                   const float* __restrict__ Vb,
                                                   float* __restrict__ O) {
    const int b = blockIdx.z, h = blockIdx.y, qt = blockIdx.x;
    const int tid = threadIdx.x;
    const int wid = tid >> 6, lane = tid & 63;
    const int q = qt * 64 + lane;

    // staging: per wave 2048 floats (2 bufs x (K 16x32 + V 16x32)); 4 waves = 8192
    // reduction (after barrier, aliases staging): 256 rows x 35 floats = 8960
    __shared__ float smem[8960];
    float* wbase = &smem[wid * 2048];

    float qreg[32];
    const float* qrow = Q + ((size_t)(b * LQv + q)) * Cv + h * DHv;
#pragma unroll
    for (int d = 0; d < 32; ++d) qreg[d] = qrow[d];

    const float* kb0 = Kb + ((size_t)(b * LQv + wid * 256)) * Cv + h * DHv;
    const float* vb0 = Vb + ((size_t)(b * LQv + wid * 256)) * Cv + h * DHv;

    float mval = -1e30f, lsum = 0.f;
    float acc[32] = {};
    const float scale = 0.17677669529663687f;  // 1/sqrt(32)

    // prefetch registers: 2 float4 of K + 2 of V per lane per chunk
    float4 pk0, pk1, pv0, pv1;
    const int e0 = lane, e1 = lane + 64;          // float4 slot ids in 16x32 chunk
    const size_t ko0 = (size_t)(e0 >> 3) * Cv + ((e0 & 7) << 2);
    const size_t ko1 = (size_t)(e1 >> 3) * Cv + ((e1 & 7) << 2);

    auto gload = [&](int c) {
        const float* kc = kb0 + (size_t)c * 16 * Cv;
        const float* vc = vb0 + (size_t)c * 16 * Cv;
        pk0 = *(const float4*)(kc + ko0);
        pk1 = *(const float4*)(kc + ko1);
        pv0 = *(const float4*)(vc + ko0);
        pv1 = *(const float4*)(vc + ko1);
    };
    auto swrite = [&](int buf) {
        float* kd = wbase + buf * 1024;
        float* vd = kd + 512;
        *(float4*)(kd + (lane << 2))       = pk0;
        *(float4*)(kd + (lane << 2) + 256) = pk1;
        *(float4*)(vd + (lane << 2))       = pv0;
        *(float4*)(vd + (lane << 2) + 256) = pv1;
    };
    auto compute = [&](int buf) {
        const float* kd = wbase + buf * 1024;
        const float* vd = kd + 512;
        float s[16];
        float cmax = mval;
#pragma unroll
        for (int j = 0; j < 16; ++j) {
            float dot = 0.f;
#pragma unroll
            for (int d4 = 0; d4 < 8; ++d4) {
                float4 k4 = *(const float4*)(kd + j * 32 + (d4 << 2));  // broadcast
                dot = fmaf(qreg[d4 * 4 + 0], k4.x, dot);
                dot = fmaf(qreg[d4 * 4 + 1], k4.y, dot);
                dot = fmaf(qreg[d4 * 4 + 2], k4.z, dot);
                dot = fmaf(qreg[d4 * 4 + 3], k4.w, dot);
            }
            s[j] = dot * scale;
            cmax = fmaxf(cmax, s[j]);
        }
        float corr = __expf(mval - cmax);
        mval = cmax;
        lsum *= corr;
#pragma unroll
        for (int d = 0; d < 32; ++d) acc[d] *= corr;
#pragma unroll
        for (int j = 0; j < 16; ++j) {
            float p = __expf(s[j] - cmax);
            lsum += p;
#pragma unroll
            for (int d4 = 0; d4 < 8; ++d4) {
                float4 v4 = *(const float4*)(vd + j * 32 + (d4 << 2));  // broadcast
                acc[d4 * 4 + 0] = fmaf(p, v4.x, acc[d4 * 4 + 0]);
                acc[d4 * 4 + 1] = fmaf(p, v4.y, acc[d4 * 4 + 1]);
                acc[d4 * 4 + 2] = fmaf(p, v4.z, acc[d4 * 4 + 2]);
                acc[d4 * 4 + 3] = fmaf(p, v4.w, acc[d4 * 4 + 3]);
            }
        }
    };

    gload(0);
    swrite(0);
#pragma unroll 2
    for (int c = 0; c < 16; ++c) {
        if (c < 15) gload(c + 1);      // prefetch next chunk (global, in flight)
        compute(c & 1);
        if (c < 15) swrite((c + 1) & 1);
    }

    // merge the 4 per-wave partial states through LDS (row stride 35: odd,
    // coprime with 32 banks -> conflict-light)
    __syncthreads();
    float* myrow = &smem[(wid * 64 + lane) * 35];
    myrow[0] = mval;
    myrow[1] = lsum;
#pragma unroll
    for (int d = 0; d < 32; ++d) myrow[2 + d] = acc[d];
    __syncthreads();
    if (wid == 0) {
        float m = -1e30f;
#pragma unroll
        for (int w = 0; w < 4; ++w) m = fmaxf(m, smem[(w * 64 + lane) * 35]);
        float l = 0.f, o[32] = {};
#pragma unroll
        for (int w = 0; w < 4; ++w) {
            const float* rw = &smem[(w * 64 + lane) * 35];
            float cc = __expf(rw[0] - m);
            l += rw[1] * cc;
#pragma unroll
            for (int d = 0; d < 32; ++d) o[d] = fmaf(cc, rw[2 + d], o[d]);
        }
        float inv = 1.f / l;
        float* orow = O + ((size_t)(b * LQv + q)) * Cv + h * DHv;
#pragma unroll
        for (int d4 = 0; d4 < 8; ++d4) {
            float4 o4;
            o4.x = o[d4 * 4 + 0] * inv; o4.y = o[d4 * 4 + 1] * inv;
            o4.z = o[d4 * 4 + 2] * inv; o4.w = o[d4 * 4 + 3] * inv;
            *(float4*)(orow + (d4 << 2)) = o4;
        }
    }
}

// ---------------------------------------------------------------------------
// Deformable sampling. grid: B*LQ blocks, 256 threads: thread = (h, d).
__global__ __launch_bounds__(256) void deform_sample(const float* __restrict__ value,
                                                     const float* __restrict__ offs,
                                                     const float* __restrict__ awl,
                                                     const float* __restrict__ ref,
                                                     float* __restrict__ out) {
    const int bq = blockIdx.x;          // b*LQ + q
    const int b = bq >> 10;
    const int tid = threadIdx.x;
    const int h = tid >> 5, d = tid & 31;

    // softmax over the 16 (l,p) attention-weight logits of this head
    const float* aw = awl + (size_t)bq * (Hv * Lv * Pv) + h * 16;
    float w[16];
    float mx = -1e30f;
#pragma unroll
    for (int j = 0; j < 16; ++j) { w[j] = aw[j]; mx = fmaxf(mx, w[j]); }
    float ssum = 0.f;
#pragma unroll
    for (int j = 0; j < 16; ++j) { w[j] = __expf(w[j] - mx); ssum += w[j]; }
    float invs = 1.f / ssum;

    const float* op = offs + (size_t)bq * 256 + h * 32;   // (L,P,2) for this head
    const float* rp = ref + (size_t)bq * (Lv * 2);

    const int starts[4] = {0, 16384, 20480, 21504};
    const int WHl[4] = {128, 64, 32, 16};

    float acc = 0.f;
#pragma unroll 1
    for (int l = 0; l < 4; ++l) {
        const int wl = WHl[l];
        const float rx = rp[l * 2 + 0], ry = rp[l * 2 + 1];
        const float* vbase = value + ((size_t)b * LSRCv + starts[l]) * Cv + h * DHv + d;
#pragma unroll 1
        for (int p = 0; p < 4; ++p) {
            float ox = op[l * 8 + p * 2 + 0], oy = op[l * 8 + p * 2 + 1];
            // (ref + off/norm)*wl - 0.5 == ref*wl + off - 0.5  (square levels)
            float x = rx * (float)wl + ox - 0.5f;
            float y = ry * (float)wl + oy - 0.5f;
            float fx0 = floorf(x), fy0 = floorf(y);
            int x0 = (int)fx0, y0 = (int)fy0;
            float tx = x - fx0, ty = y - fy0;
            float w00 = (1.f - tx) * (1.f - ty);
            float w10 = tx * (1.f - ty);
            float w01 = (1.f - tx) * ty;
            float w11 = tx * ty;
            float s = 0.f;
            bool xin0 = (x0 >= 0) & (x0 < wl);
            bool xin1 = (x0 + 1 >= 0) & (x0 + 1 < wl);
            bool yin0 = (y0 >= 0) & (y0 < wl);
            bool yin1 = (y0 + 1 >= 0) & (y0 + 1 < wl);
            if (yin0) {
                if (xin0) s = fmaf(w00, vbase[(size_t)(y0 * wl + x0) * Cv], s);
                if (xin1) s = fmaf(w10, vbase[(size_t)(y0 * wl + x0 + 1) * Cv], s);
            }
            if (yin1) {
                if (xin0) s = fmaf(w01, vbase[(size_t)((y0 + 1) * wl + x0) * Cv], s);
                if (xin1) s = fmaf(w11, vbase[(size_t)((y0 + 1) * wl + x0 + 1) * Cv], s);
            }
            acc = fmaf(w[l * 4 + p] * invs, s, acc);
        }
    }
    out[(size_t)bq * Cv + h * DHv + d] = acc;
}

// ---------------------------------------------------------------------------
// out = LayerNorm(x + r) * g + b    one block per row of 256
__global__ __launch_bounds__(256) void ln_residual(const float* __restrict__ x,
                                                   const float* __restrict__ r,
                                                   const float* __restrict__ g,
                                                   const float* __restrict__ bta,
                                                   float* __restrict__ out) {
    const int row = blockIdx.x;
    const int tid = threadIdx.x;
    float v = x[(size_t)row * Cv + tid] + r[(size_t)row * Cv + tid];
    float s = v, sq = v * v;
#pragma unroll
    for (int off = 32; off > 0; off >>= 1) {
        s  += __shfl_down(s, off, 64);
        sq += __shfl_down(sq, off, 64);
    }
    __shared__ float ss[4], sqq[4];
    int wid = tid >> 6;
    if ((tid & 63) == 0) { ss[wid] = s; sqq[wid] = sq; }
    __syncthreads();
    __shared__ float meansh, rstdsh;
    if (tid == 0) {
        float S = ss[0] + ss[1] + ss[2] + ss[3];
        float Q = sqq[0] + sqq[1] + sqq[2] + sqq[3];
        float mean = S * (1.f / Cv);
        float var = Q * (1.f / Cv) - mean * mean;
        meansh = mean;
        rstdsh = rsqrtf(var + 1e-5f);
    }
    __syncthreads();
    out[(size_t)row * Cv + tid] = (v - meansh) * rstdsh * g[tid] + bta[tid];
}

// ---------------------------------------------------------------------------
extern "C" void kernel_launch(void* const* d_in, const int* in_sizes, int n_in,
                              void* d_out, int out_size, void* d_ws, size_t ws_size,
                              hipStream_t stream) {
    const float* tgt       = (const float*)d_in[0];
    const float* query_pos = (const float*)d_in[1];
    const float* ref_pts   = (const float*)d_in[2];
    const float* src       = (const float*)d_in[3];
    const float* in_w      = (const float*)d_in[4];
    const float* in_b      = (const float*)d_in[5];
    const float* sa_w      = (const float*)d_in[6];
    const float* sa_b      = (const float*)d_in[7];
    const float* off_w     = (const float*)d_in[8];
    const float* off_b     = (const float*)d_in[9];
    const float* aw_w      = (const float*)d_in[10];
    const float* aw_b      = (const float*)d_in[11];
    const float* val_w     = (const float*)d_in[12];
    const float* val_b     = (const float*)d_in[13];
    const float* co_w      = (const float*)d_in[14];
    const float* co_b      = (const float*)d_in[15];
    const float* ln1_g     = (const float*)d_in[16];
    const float* ln1_b     = (const float*)d_in[17];
    const float* ln2_g     = (const float*)d_in[18];
    const float* ln2_b     = (const float*)d_in[19];
    const float* ln3_g     = (const float*)d_in[20];
    const float* ln3_b     = (const float*)d_in[21];
    const float* f1_w      = (const float*)d_in[22];
    const float* f1_b      = (const float*)d_in[23];
    const float* f2_w      = (const float*)d_in[24];
    const float* f2_b      = (const float*)d_in[25];

    const int M0  = Bv * LQv * Cv;          // 1048576
    const int VSZ = Bv * LSRCv * Cv;        // 22282240
    float* ws = (float*)d_ws;

    // Phase-A buffers alias the (later) value region — lifetimes don't overlap.
    float* big    = ws;                     // VSZ floats
    float* qk     = big;
    float* qb     = big + (size_t)M0;
    float* kb     = big + (size_t)2 * M0;
    float* vb     = big + (size_t)3 * M0;
    float* ob     = big + (size_t)4 * M0;
    float* value  = big;
    float* tgt_a  = ws + (size_t)VSZ;
    float* query  = tgt_a + M0;
    float* offs   = query + M0;
    float* awb    = offs + M0;              // B*LQ*128
    float* sampled= awb + (size_t)Bv * LQv * 128;
    float* tgt_b  = sampled + M0;
    float* hidden = tgt_b + M0;             // B*LQ*DFF
    float* tmp    = hidden + (size_t)Bv * LQv * DFFv;

    const int Mq = Bv * LQv;                // 4096 rows
    dim3 blk256(256);

    // 1. qk = tgt + query_pos
    add_kernel<<<dim3(M0 / 4 / 256), blk256, 0, stream>>>(tgt, query_pos, qk, M0 / 4);

    // 2. q,k,v projections
    gemm_bias<<<dim3(Cv / BN, Mq / BM), blk256, 0, stream>>>(qk, in_w,                    in_b,       qb, Mq, Cv, Cv, 0);
    gemm_bias<<<dim3(Cv / BN, Mq / BM), blk256, 0, stream>>>(qk, in_w + (size_t)Cv * Cv,  in_b + Cv,  kb, Mq, Cv, Cv, 0);
    gemm_bias<<<dim3(Cv / BN, Mq / BM), blk256, 0, stream>>>(tgt, in_w + (size_t)2*Cv*Cv, in_b + 2*Cv, vb, Mq, Cv, Cv, 0);

    // 3. self-attention (4-wave key-split flash, LDS-staged K/V)
    attn_kernel<<<dim3(LQv / 64, Hv, Bv), blk256, 0, stream>>>(qb, kb, vb, ob);

    // 4. output projection, 5. LN2 residual
    gemm_bias<<<dim3(Cv / BN, Mq / BM), blk256, 0, stream>>>(ob, sa_w, sa_b, tmp, Mq, Cv, Cv, 0);
    ln_residual<<<dim3(Mq), blk256, 0, stream>>>(tgt, tmp, ln2_g, ln2_b, tgt_a);

    // 6. query = tgt_a + query_pos
    add_kernel<<<dim3(M0 / 4 / 256), blk256, 0, stream>>>(tgt_a, query_pos, query, M0 / 4);

    // 7. value projection (the big GEMM)
    gemm_bias<<<dim3(Cv / BN, (Bv * LSRCv) / BM), blk256, 0, stream>>>(src, val_w, val_b, value, Bv * LSRCv, Cv, Cv, 0);

    // 8. offsets, 9. attention-weight logits
    gemm_bias<<<dim3(Cv / BN, Mq / BM), blk256, 0, stream>>>(query, off_w, off_b, offs, Mq, Cv, Cv, 0);
    gemm_bias<<<dim3(128 / BN, Mq / BM), blk256, 0, stream>>>(query, aw_w, aw_b, awb, Mq, 128, Cv, 0);

    // 10. deformable bilinear sampling
    deform_sample<<<dim3(Bv * LQv), blk256, 0, stream>>>(value, offs, awb, ref_pts, sampled);

    // 11. cross-attn output projection, 12. LN1 residual
    gemm_bias<<<dim3(Cv / BN, Mq / BM), blk256, 0, stream>>>(sampled, co_w, co_b, tmp, Mq, Cv, Cv, 0);
    ln_residual<<<dim3(Mq), blk256, 0, stream>>>(tgt_a, tmp, ln1_g, ln1_b, tgt_b);

    // 13./14. FFN, 15. LN3 → d_out
    gemm_bias<<<dim3(DFFv / BN, Mq / BM), blk256, 0, stream>>>(tgt_b, f1_w, f1_b, hidden, Mq, DFFv, Cv, 1);
    gemm_bias<<<dim3(Cv / BN, Mq / BM), blk256, 0, stream>>>(hidden, f2_w, f2_b, tmp, Mq, Cv, DFFv, 0);
    ln_residual<<<dim3(Mq), blk256, 0, stream>>>(tgt_b, tmp, ln3_g, ln3_b, (float*)d_out);
}

// Round 4
// 822.692 us; speedup vs baseline: 6.7199x; 6.7199x over previous
//
#include <hip/hip_runtime.h>
#include <hip/hip_bf16.h>
#include <math.h>

// Problem constants
#define Bv   4
#define LQv  1024
#define Cv   256
#define Hv   8
#define Lv   4
#define Pv   4
#define DFFv 1024
#define DHv  32
#define LSRCv 21760   // 128*128 + 64*64 + 32*32 + 16*16

typedef __attribute__((ext_vector_type(8))) short bhalf8;   // 8 bf16 (4 VGPRs)
typedef __attribute__((ext_vector_type(4))) float floatx4;  // MFMA acc

// fp32 -> bf16 RNE, packed pair
__device__ inline unsigned pk_bf16x2(float x, float y) {
    unsigned xb = __float_as_uint(x), yb = __float_as_uint(y);
    unsigned xr = (xb + 0x7FFFu + ((xb >> 16) & 1u)) >> 16;
    unsigned yr = (yb + 0x7FFFu + ((yb >> 16) & 1u)) >> 16;
    return xr | (yr << 16);
}

// ---------------------------------------------------------------------------
// elementwise add: out = a + b   (float4 vectorized)
__global__ __launch_bounds__(256) void add_kernel(const float* __restrict__ a,
                                                  const float* __restrict__ b,
                                                  float* __restrict__ out, int n4) {
    int i = blockIdx.x * blockDim.x + threadIdx.x;
    if (i < n4) {
        float4 av = ((const float4*)a)[i];
        float4 bv = ((const float4*)b)[i];
        float4 o;
        o.x = av.x + bv.x; o.y = av.y + bv.y; o.z = av.z + bv.z; o.w = av.w + bv.w;
        ((float4*)out)[i] = o;
    }
}

// ---------------------------------------------------------------------------
// bf16-MFMA GEMM: C[M,N] = A[M,K] @ W[N,K]^T + bias[N], optional relu.
// fp32 inputs, converted to bf16 (RNE) during LDS staging.
// 128x128 tile, BK=32, 256 threads = 4 waves, each wave a 64x64 sub-tile
// (4x4 frags of 16x16). Requires M%128==0, N%128==0, K%32==0.
__global__ __launch_bounds__(256) void gemm_mfma(const float* __restrict__ A,
                                                 const float* __restrict__ W,
                                                 const float* __restrict__ bias,
                                                 float* __restrict__ Cmat,
                                                 int M, int N, int K, int relu) {
    __shared__ unsigned short As[128 * 32];   // bf16, K-major rows of 32
    __shared__ unsigned short Bs[128 * 32];
    const int bm = blockIdx.y * 128;
    const int bn = blockIdx.x * 128;
    const int tid = threadIdx.x;
    const int wid = tid >> 6, lane = tid & 63;
    const int wm = (wid >> 1) * 64, wn = (wid & 1) * 64;
    const int col16 = lane & 15;      // m for A-frag, n for B-frag, col for D
    const int quad = lane >> 4;       // k-group for A/B frags, row-group for D

    const int r = tid >> 1;           // staging row 0..127
    const int half = tid & 1;         // k-half (16 floats)
    const float* aptr = A + (size_t)(bm + r) * K + (half << 4);
    const float* wptr = W + (size_t)(bn + r) * K + (half << 4);
    unsigned* as_dst = (unsigned*)As + r * 16 + (half << 3);
    unsigned* bs_dst = (unsigned*)Bs + r * 16 + (half << 3);

    floatx4 acc[4][4] = {};

    for (int kc = 0; kc < K; kc += 32) {
        const float4* ap = (const float4*)(aptr + kc);
        const float4* wp = (const float4*)(wptr + kc);
        float4 a0 = ap[0], a1 = ap[1], a2 = ap[2], a3 = ap[3];
        float4 w0 = wp[0], w1 = wp[1], w2 = wp[2], w3 = wp[3];
        uint4 au0 = {pk_bf16x2(a0.x, a0.y), pk_bf16x2(a0.z, a0.w),
                     pk_bf16x2(a1.x, a1.y), pk_bf16x2(a1.z, a1.w)};
        uint4 au1 = {pk_bf16x2(a2.x, a2.y), pk_bf16x2(a2.z, a2.w),
                     pk_bf16x2(a3.x, a3.y), pk_bf16x2(a3.z, a3.w)};
        uint4 wu0 = {pk_bf16x2(w0.x, w0.y), pk_bf16x2(w0.z, w0.w),
                     pk_bf16x2(w1.x, w1.y), pk_bf16x2(w1.z, w1.w)};
        uint4 wu1 = {pk_bf16x2(w2.x, w2.y), pk_bf16x2(w2.z, w2.w),
                     pk_bf16x2(w3.x, w3.y), pk_bf16x2(w3.z, w3.w)};
        *(uint4*)as_dst = au0;
        *(uint4*)(as_dst + 4) = au1;
        *(uint4*)bs_dst = wu0;
        *(uint4*)(bs_dst + 4) = wu1;
        __syncthreads();

        bhalf8 af[4], bf[4];
#pragma unroll
        for (int mt = 0; mt < 4; ++mt)
            af[mt] = *(const bhalf8*)&As[(wm + mt * 16 + col16) * 32 + quad * 8];
#pragma unroll
        for (int nt = 0; nt < 4; ++nt)
            bf[nt] = *(const bhalf8*)&Bs[(wn + nt * 16 + col16) * 32 + quad * 8];
#pragma unroll
        for (int mt = 0; mt < 4; ++mt)
#pragma unroll
            for (int nt = 0; nt < 4; ++nt)
                acc[mt][nt] = __builtin_amdgcn_mfma_f32_16x16x32_bf16(
                    af[mt], bf[nt], acc[mt][nt], 0, 0, 0);
        __syncthreads();
    }

    // epilogue: D row = quad*4 + i, col = col16  (verified C/D layout)
#pragma unroll
    for (int mt = 0; mt < 4; ++mt) {
#pragma unroll
        for (int nt = 0; nt < 4; ++nt) {
            const int col = bn + wn + nt * 16 + col16;
            const float bv = bias[col];
#pragma unroll
            for (int i = 0; i < 4; ++i) {
                const int row = bm + wm + mt * 16 + quad * 4 + i;
                float v = acc[mt][nt][i] + bv;
                if (relu) v = fmaxf(v, 0.f);
                Cmat[(size_t)row * N + col] = v;
            }
        }
    }
}

// ---------------------------------------------------------------------------
// fp32 GEMM (kept for the offsets projection — sampling-location precision)
#define BM 64
#define BN 64
#define BKt 16
__global__ __launch_bounds__(256) void gemm_bias(const float* __restrict__ A,
                                                 const float* __restrict__ W,
                                                 const float* __restrict__ bias,
                                                 float* __restrict__ Cmat,
                                                 int M, int N, int K, int relu) {
    __shared__ float As[BKt][BM];
    __shared__ float Bs[BKt][BN];
    const int bm = blockIdx.y * BM;
    const int bn = blockIdx.x * BN;
    const int tid = threadIdx.x;
    const int tr = (tid >> 4) << 2;
    const int tc = (tid & 15) << 2;
    float acc[4][4] = {};

    const int lrow = tid >> 2;
    const int lc4  = (tid & 3) << 2;
    const float* Aptr = A + (size_t)(bm + lrow) * K + lc4;
    const float* Wptr = W + (size_t)(bn + lrow) * K + lc4;

    for (int k0 = 0; k0 < K; k0 += BKt) {
        float4 a4 = *(const float4*)(Aptr + k0);
        float4 w4 = *(const float4*)(Wptr + k0);
        As[lc4 + 0][lrow] = a4.x; As[lc4 + 1][lrow] = a4.y;
        As[lc4 + 2][lrow] = a4.z; As[lc4 + 3][lrow] = a4.w;
        Bs[lc4 + 0][lrow] = w4.x; Bs[lc4 + 1][lrow] = w4.y;
        Bs[lc4 + 2][lrow] = w4.z; Bs[lc4 + 3][lrow] = w4.w;
        __syncthreads();
#pragma unroll
        for (int kk = 0; kk < BKt; ++kk) {
            float a0 = As[kk][tr + 0], a1 = As[kk][tr + 1];
            float a2 = As[kk][tr + 2], a3 = As[kk][tr + 3];
            float b0 = Bs[kk][tc + 0], b1 = Bs[kk][tc + 1];
            float b2 = Bs[kk][tc + 2], b3 = Bs[kk][tc + 3];
            acc[0][0] = fmaf(a0, b0, acc[0][0]); acc[0][1] = fmaf(a0, b1, acc[0][1]);
            acc[0][2] = fmaf(a0, b2, acc[0][2]); acc[0][3] = fmaf(a0, b3, acc[0][3]);
            acc[1][0] = fmaf(a1, b0, acc[1][0]); acc[1][1] = fmaf(a1, b1, acc[1][1]);
            acc[1][2] = fmaf(a1, b2, acc[1][2]); acc[1][3] = fmaf(a1, b3, acc[1][3]);
            acc[2][0] = fmaf(a2, b0, acc[2][0]); acc[2][1] = fmaf(a2, b1, acc[2][1]);
            acc[2][2] = fmaf(a2, b2, acc[2][2]); acc[2][3] = fmaf(a2, b3, acc[2][3]);
            acc[3][0] = fmaf(a3, b0, acc[3][0]); acc[3][1] = fmaf(a3, b1, acc[3][1]);
            acc[3][2] = fmaf(a3, b2, acc[3][2]); acc[3][3] = fmaf(a3, b3, acc[3][3]);
        }
        __syncthreads();
    }
#pragma unroll
    for (int i = 0; i < 4; ++i) {
#pragma unroll
        for (int j = 0; j < 4; ++j) {
            float v = acc[i][j] + bias[bn + tc + j];
            if (relu) v = fmaxf(v, 0.f);
            Cmat[(size_t)(bm + tr + i) * N + bn + tc + j] = v;
        }
    }
}

// ---------------------------------------------------------------------------
// Flash-style self-attention, key-split across 4 waves (Round-2 version).
// grid: (LQ/64, H, B), block: 256 (4 waves). lane = query.
// K/V rows are lane-uniform addresses -> scalar/broadcast loads, no LDS in
// the hot loop. Partial (m,l,acc) merged through LDS.
__global__ __launch_bounds__(256) void attn_kernel(const float* __restrict__ Q,
                                                   const float* __restrict__ Kb,
                                                   const float* __restrict__ Vb,
                                                   float* __restrict__ O) {
    const int b = blockIdx.z, h = blockIdx.y, qt = blockIdx.x;
    const int tid = threadIdx.x;
    const int wid = tid >> 6, lane = tid & 63;
    const int q = qt * 64 + lane;

    float qreg[32];
    const float* qrow = Q + ((size_t)(b * LQv + q)) * Cv + h * DHv;
#pragma unroll
    for (int d = 0; d < 32; ++d) qreg[d] = qrow[d];

    const float* kbase = Kb + ((size_t)(b * LQv)) * Cv + h * DHv;
    const float* vbase = Vb + ((size_t)(b * LQv)) * Cv + h * DHv;

    float mval = -1e30f, lsum = 0.f;
    float acc[32] = {};
    const float scale = 0.17677669529663687f;  // 1/sqrt(32)

#pragma unroll 1
    for (int c = 0; c < 16; ++c) {
        const int k0 = wid * 256 + c * 16;
        float s[16];
        float cmax = mval;
#pragma unroll
        for (int j = 0; j < 16; ++j) {
            const float* kr = kbase + (size_t)(k0 + j) * Cv;   // lane-uniform
            float dot = 0.f;
#pragma unroll
            for (int d = 0; d < 32; ++d) dot = fmaf(qreg[d], kr[d], dot);
            s[j] = dot * scale;
            cmax = fmaxf(cmax, s[j]);
        }
        float corr = __expf(mval - cmax);
        mval = cmax;
        lsum *= corr;
#pragma unroll
        for (int d = 0; d < 32; ++d) acc[d] *= corr;
#pragma unroll
        for (int j = 0; j < 16; ++j) {
            float p = __expf(s[j] - cmax);
            lsum += p;
            const float* vr = vbase + (size_t)(k0 + j) * Cv;   // lane-uniform
#pragma unroll
            for (int d = 0; d < 32; ++d) acc[d] = fmaf(p, vr[d], acc[d]);
        }
    }

    // merge the 4 per-wave partial states
    __shared__ float red[4][64][35];
    red[wid][lane][0] = mval;
    red[wid][lane][1] = lsum;
#pragma unroll
    for (int d = 0; d < 32; ++d) red[wid][lane][2 + d] = acc[d];
    __syncthreads();
    if (wid == 0) {
        float m = red[0][lane][0];
#pragma unroll
        for (int w = 1; w < 4; ++w) m = fmaxf(m, red[w][lane][0]);
        float l = 0.f, o[32] = {};
#pragma unroll
        for (int w = 0; w < 4; ++w) {
            float cc = __expf(red[w][lane][0] - m);
            l += red[w][lane][1] * cc;
#pragma unroll
            for (int d = 0; d < 32; ++d) o[d] = fmaf(cc, red[w][lane][2 + d], o[d]);
        }
        float inv = 1.f / l;
        float* orow = O + ((size_t)(b * LQv + q)) * Cv + h * DHv;
#pragma unroll
        for (int d = 0; d < 32; ++d) orow[d] = o[d] * inv;
    }
}

// ---------------------------------------------------------------------------
// Deformable sampling. grid: B*LQ blocks, 256 threads: thread = (h, d).
__global__ __launch_bounds__(256) void deform_sample(const float* __restrict__ value,
                                                     const float* __restrict__ offs,
                                                     const float* __restrict__ awl,
                                                     const float* __restrict__ ref,
                                                     float* __restrict__ out) {
    const int bq = blockIdx.x;          // b*LQ + q
    const int b = bq >> 10;
    const int tid = threadIdx.x;
    const int h = tid >> 5, d = tid & 31;

    const float* aw = awl + (size_t)bq * (Hv * Lv * Pv) + h * 16;
    float w[16];
    float mx = -1e30f;
#pragma unroll
    for (int j = 0; j < 16; ++j) { w[j] = aw[j]; mx = fmaxf(mx, w[j]); }
    float ssum = 0.f;
#pragma unroll
    for (int j = 0; j < 16; ++j) { w[j] = __expf(w[j] - mx); ssum += w[j]; }
    float invs = 1.f / ssum;

    const float* op = offs + (size_t)bq * 256 + h * 32;
    const float* rp = ref + (size_t)bq * (Lv * 2);

    const int starts[4] = {0, 16384, 20480, 21504};
    const int WHl[4] = {128, 64, 32, 16};

    float acc = 0.f;
#pragma unroll 1
    for (int l = 0; l < 4; ++l) {
        const int wl = WHl[l];
        const float rx = rp[l * 2 + 0], ry = rp[l * 2 + 1];
        const float* vbase = value + ((size_t)b * LSRCv + starts[l]) * Cv + h * DHv + d;
#pragma unroll 1
        for (int p = 0; p < 4; ++p) {
            float ox = op[l * 8 + p * 2 + 0], oy = op[l * 8 + p * 2 + 1];
            float x = rx * (float)wl + ox - 0.5f;
            float y = ry * (float)wl + oy - 0.5f;
            float fx0 = floorf(x), fy0 = floorf(y);
            int x0 = (int)fx0, y0 = (int)fy0;
            float tx = x - fx0, ty = y - fy0;
            float w00 = (1.f - tx) * (1.f - ty);
            float w10 = tx * (1.f - ty);
            float w01 = (1.f - tx) * ty;
            float w11 = tx * ty;
            float s = 0.f;
            bool xin0 = (x0 >= 0) & (x0 < wl);
            bool xin1 = (x0 + 1 >= 0) & (x0 + 1 < wl);
            bool yin0 = (y0 >= 0) & (y0 < wl);
            bool yin1 = (y0 + 1 >= 0) & (y0 + 1 < wl);
            if (yin0) {
                if (xin0) s = fmaf(w00, vbase[(size_t)(y0 * wl + x0) * Cv], s);
                if (xin1) s = fmaf(w10, vbase[(size_t)(y0 * wl + x0 + 1) * Cv], s);
            }
            if (yin1) {
                if (xin0) s = fmaf(w01, vbase[(size_t)((y0 + 1) * wl + x0) * Cv], s);
                if (xin1) s = fmaf(w11, vbase[(size_t)((y0 + 1) * wl + x0 + 1) * Cv], s);
            }
            acc = fmaf(w[l * 4 + p] * invs, s, acc);
        }
    }
    out[(size_t)bq * Cv + h * DHv + d] = acc;
}

// ---------------------------------------------------------------------------
// out = LayerNorm(x + r) * g + b    one block per row of 256
__global__ __launch_bounds__(256) void ln_residual(const float* __restrict__ x,
                                                   const float* __restrict__ r,
                                                   const float* __restrict__ g,
                                                   const float* __restrict__ bta,
                                                   float* __restrict__ out) {
    const int row = blockIdx.x;
    const int tid = threadIdx.x;
    float v = x[(size_t)row * Cv + tid] + r[(size_t)row * Cv + tid];
    float s = v, sq = v * v;
#pragma unroll
    for (int off = 32; off > 0; off >>= 1) {
        s  += __shfl_down(s, off, 64);
        sq += __shfl_down(sq, off, 64);
    }
    __shared__ float ss[4], sqq[4];
    int wid = tid >> 6;
    if ((tid & 63) == 0) { ss[wid] = s; sqq[wid] = sq; }
    __syncthreads();
    __shared__ float meansh, rstdsh;
    if (tid == 0) {
        float S = ss[0] + ss[1] + ss[2] + ss[3];
        float Q = sqq[0] + sqq[1] + sqq[2] + sqq[3];
        float mean = S * (1.f / Cv);
        float var = Q * (1.f / Cv) - mean * mean;
        meansh = mean;
        rstdsh = rsqrtf(var + 1e-5f);
    }
    __syncthreads();
    out[(size_t)row * Cv + tid] = (v - meansh) * rstdsh * g[tid] + bta[tid];
}

// ---------------------------------------------------------------------------
extern "C" void kernel_launch(void* const* d_in, const int* in_sizes, int n_in,
                              void* d_out, int out_size, void* d_ws, size_t ws_size,
                              hipStream_t stream) {
    const float* tgt       = (const float*)d_in[0];
    const float* query_pos = (const float*)d_in[1];
    const float* ref_pts   = (const float*)d_in[2];
    const float* src       = (const float*)d_in[3];
    const float* in_w      = (const float*)d_in[4];
    const float* in_b      = (const float*)d_in[5];
    const float* sa_w      = (const float*)d_in[6];
    const float* sa_b      = (const float*)d_in[7];
    const float* off_w     = (const float*)d_in[8];
    const float* off_b     = (const float*)d_in[9];
    const float* aw_w      = (const float*)d_in[10];
    const float* aw_b      = (const float*)d_in[11];
    const float* val_w     = (const float*)d_in[12];
    const float* val_b     = (const float*)d_in[13];
    const float* co_w      = (const float*)d_in[14];
    const float* co_b      = (const float*)d_in[15];
    const float* ln1_g     = (const float*)d_in[16];
    const float* ln1_b     = (const float*)d_in[17];
    const float* ln2_g     = (const float*)d_in[18];
    const float* ln2_b     = (const float*)d_in[19];
    const float* ln3_g     = (const float*)d_in[20];
    const float* ln3_b     = (const float*)d_in[21];
    const float* f1_w      = (const float*)d_in[22];
    const float* f1_b      = (const float*)d_in[23];
    const float* f2_w      = (const float*)d_in[24];
    const float* f2_b      = (const float*)d_in[25];

    const int M0  = Bv * LQv * Cv;          // 1048576
    const int VSZ = Bv * LSRCv * Cv;        // 22282240
    float* ws = (float*)d_ws;

    // Phase-A buffers alias the (later) value region — lifetimes don't overlap.
    float* big    = ws;                     // VSZ floats
    float* qk     = big;
    float* qb     = big + (size_t)M0;
    float* kb     = big + (size_t)2 * M0;
    float* vb     = big + (size_t)3 * M0;
    float* ob     = big + (size_t)4 * M0;
    float* value  = big;
    float* tgt_a  = ws + (size_t)VSZ;
    float* query  = tgt_a + M0;
    float* offs   = query + M0;
    float* awb    = offs + M0;              // B*LQ*128
    float* sampled= awb + (size_t)Bv * LQv * 128;
    float* tgt_b  = sampled + M0;
    float* hidden = tgt_b + M0;             // B*LQ*DFF
    float* tmp    = hidden + (size_t)Bv * LQv * DFFv;

    const int Mq = Bv * LQv;                // 4096 rows
    dim3 blk256(256);

    // 1. qk = tgt + query_pos
    add_kernel<<<dim3(M0 / 4 / 256), blk256, 0, stream>>>(tgt, query_pos, qk, M0 / 4);

    // 2. q,k,v projections (bf16 MFMA)
    gemm_mfma<<<dim3(Cv / 128, Mq / 128), blk256, 0, stream>>>(qk, in_w,                    in_b,       qb, Mq, Cv, Cv, 0);
    gemm_mfma<<<dim3(Cv / 128, Mq / 128), blk256, 0, stream>>>(qk, in_w + (size_t)Cv * Cv,  in_b + Cv,  kb, Mq, Cv, Cv, 0);
    gemm_mfma<<<dim3(Cv / 128, Mq / 128), blk256, 0, stream>>>(tgt, in_w + (size_t)2*Cv*Cv, in_b + 2*Cv, vb, Mq, Cv, Cv, 0);

    // 3. self-attention (4-wave key-split flash)
    attn_kernel<<<dim3(LQv / 64, Hv, Bv), blk256, 0, stream>>>(qb, kb, vb, ob);

    // 4. output projection, 5. LN2 residual
    gemm_mfma<<<dim3(Cv / 128, Mq / 128), blk256, 0, stream>>>(ob, sa_w, sa_b, tmp, Mq, Cv, Cv, 0);
    ln_residual<<<dim3(Mq), blk256, 0, stream>>>(tgt, tmp, ln2_g, ln2_b, tgt_a);

    // 6. query = tgt_a + query_pos
    add_kernel<<<dim3(M0 / 4 / 256), blk256, 0, stream>>>(tgt_a, query_pos, query, M0 / 4);

    // 7. value projection (the big GEMM, bf16 MFMA)
    gemm_mfma<<<dim3(Cv / 128, (Bv * LSRCv) / 128), blk256, 0, stream>>>(src, val_w, val_b, value, Bv * LSRCv, Cv, Cv, 0);

    // 8. offsets (fp32 — sampling-location precision), 9. aw logits (bf16)
    gemm_bias<<<dim3(Cv / BN, Mq / BM), blk256, 0, stream>>>(query, off_w, off_b, offs, Mq, Cv, Cv, 0);
    gemm_mfma<<<dim3(128 / 128, Mq / 128), blk256, 0, stream>>>(query, aw_w, aw_b, awb, Mq, 128, Cv, 0);

    // 10. deformable bilinear sampling
    deform_sample<<<dim3(Bv * LQv), blk256, 0, stream>>>(value, offs, awb, ref_pts, sampled);

    // 11. cross-attn output projection, 12. LN1 residual
    gemm_mfma<<<dim3(Cv / 128, Mq / 128), blk256, 0, stream>>>(sampled, co_w, co_b, tmp, Mq, Cv, Cv, 0);
    ln_residual<<<dim3(Mq), blk256, 0, stream>>>(tgt_a, tmp, ln1_g, ln1_b, tgt_b);

    // 13./14. FFN (bf16 MFMA), 15. LN3 → d_out
    gemm_mfma<<<dim3(DFFv / 128, Mq / 128), blk256, 0, stream>>>(tgt_b, f1_w, f1_b, hidden, Mq, DFFv, Cv, 1);
    gemm_mfma<<<dim3(Cv / 128, Mq / 128), blk256, 0, stream>>>(hidden, f2_w, f2_b, tmp, Mq, Cv, DFFv, 0);
    ln_residual<<<dim3(Mq), blk256, 0, stream>>>(tgt_b, tmp, ln3_g, ln3_b, (float*)d_out);
}

// Round 5
// 499.505 us; speedup vs baseline: 11.0678x; 1.6470x over previous
//
#include <hip/hip_runtime.h>
#include <hip/hip_bf16.h>
#include <math.h>

// Problem constants
#define Bv   4
#define LQv  1024
#define Cv   256
#define Hv   8
#define Lv   4
#define Pv   4
#define DFFv 1024
#define DHv  32
#define LSRCv 21760   // 128*128 + 64*64 + 32*32 + 16*16

typedef __attribute__((ext_vector_type(8))) short bhalf8;   // 8 bf16 (4 VGPRs)
typedef __attribute__((ext_vector_type(4))) float floatx4;  // MFMA acc

// fp32 -> bf16 RNE, packed pair
__device__ inline unsigned pk_bf16x2(float x, float y) {
    unsigned xb = __float_as_uint(x), yb = __float_as_uint(y);
    unsigned xr = (xb + 0x7FFFu + ((xb >> 16) & 1u)) >> 16;
    unsigned yr = (yb + 0x7FFFu + ((yb >> 16) & 1u)) >> 16;
    return xr | (yr << 16);
}

// ---------------------------------------------------------------------------
// elementwise add: out = a + b   (float4 vectorized)
__global__ __launch_bounds__(256) void add_kernel(const float* __restrict__ a,
                                                  const float* __restrict__ b,
                                                  float* __restrict__ out, int n4) {
    int i = blockIdx.x * blockDim.x + threadIdx.x;
    if (i < n4) {
        float4 av = ((const float4*)a)[i];
        float4 bv = ((const float4*)b)[i];
        float4 o;
        o.x = av.x + bv.x; o.y = av.y + bv.y; o.z = av.z + bv.z; o.w = av.w + bv.w;
        ((float4*)out)[i] = o;
    }
}

// ---------------------------------------------------------------------------
// bf16-MFMA GEMM: C[M,N] = A[M,K] @ W[N,K]^T + bias[N], optional relu.
__global__ __launch_bounds__(256) void gemm_mfma(const float* __restrict__ A,
                                                 const float* __restrict__ W,
                                                 const float* __restrict__ bias,
                                                 float* __restrict__ Cmat,
                                                 int M, int N, int K, int relu) {
    __shared__ unsigned short As[128 * 32];   // bf16, K-major rows of 32
    __shared__ unsigned short Bs[128 * 32];
    const int bm = blockIdx.y * 128;
    const int bn = blockIdx.x * 128;
    const int tid = threadIdx.x;
    const int wid = tid >> 6, lane = tid & 63;
    const int wm = (wid >> 1) * 64, wn = (wid & 1) * 64;
    const int col16 = lane & 15;
    const int quad = lane >> 4;

    const int r = tid >> 1;
    const int half = tid & 1;
    const float* aptr = A + (size_t)(bm + r) * K + (half << 4);
    const float* wptr = W + (size_t)(bn + r) * K + (half << 4);
    unsigned* as_dst = (unsigned*)As + r * 16 + (half << 3);
    unsigned* bs_dst = (unsigned*)Bs + r * 16 + (half << 3);

    floatx4 acc[4][4] = {};

    for (int kc = 0; kc < K; kc += 32) {
        const float4* ap = (const float4*)(aptr + kc);
        const float4* wp = (const float4*)(wptr + kc);
        float4 a0 = ap[0], a1 = ap[1], a2 = ap[2], a3 = ap[3];
        float4 w0 = wp[0], w1 = wp[1], w2 = wp[2], w3 = wp[3];
        uint4 au0 = {pk_bf16x2(a0.x, a0.y), pk_bf16x2(a0.z, a0.w),
                     pk_bf16x2(a1.x, a1.y), pk_bf16x2(a1.z, a1.w)};
        uint4 au1 = {pk_bf16x2(a2.x, a2.y), pk_bf16x2(a2.z, a2.w),
                     pk_bf16x2(a3.x, a3.y), pk_bf16x2(a3.z, a3.w)};
        uint4 wu0 = {pk_bf16x2(w0.x, w0.y), pk_bf16x2(w0.z, w0.w),
                     pk_bf16x2(w1.x, w1.y), pk_bf16x2(w1.z, w1.w)};
        uint4 wu1 = {pk_bf16x2(w2.x, w2.y), pk_bf16x2(w2.z, w2.w),
                     pk_bf16x2(w3.x, w3.y), pk_bf16x2(w3.z, w3.w)};
        *(uint4*)as_dst = au0;
        *(uint4*)(as_dst + 4) = au1;
        *(uint4*)bs_dst = wu0;
        *(uint4*)(bs_dst + 4) = wu1;
        __syncthreads();

        bhalf8 af[4], bf[4];
#pragma unroll
        for (int mt = 0; mt < 4; ++mt)
            af[mt] = *(const bhalf8*)&As[(wm + mt * 16 + col16) * 32 + quad * 8];
#pragma unroll
        for (int nt = 0; nt < 4; ++nt)
            bf[nt] = *(const bhalf8*)&Bs[(wn + nt * 16 + col16) * 32 + quad * 8];
#pragma unroll
        for (int mt = 0; mt < 4; ++mt)
#pragma unroll
            for (int nt = 0; nt < 4; ++nt)
                acc[mt][nt] = __builtin_amdgcn_mfma_f32_16x16x32_bf16(
                    af[mt], bf[nt], acc[mt][nt], 0, 0, 0);
        __syncthreads();
    }

#pragma unroll
    for (int mt = 0; mt < 4; ++mt) {
#pragma unroll
        for (int nt = 0; nt < 4; ++nt) {
            const int col = bn + wn + nt * 16 + col16;
            const float bv = bias[col];
#pragma unroll
            for (int i = 0; i < 4; ++i) {
                const int row = bm + wm + mt * 16 + quad * 4 + i;
                float v = acc[mt][nt][i] + bv;
                if (relu) v = fmaxf(v, 0.f);
                Cmat[(size_t)row * N + col] = v;
            }
        }
    }
}

// ---------------------------------------------------------------------------
// fp32 GEMM (kept for the offsets projection — sampling-location precision)
#define BM 64
#define BN 64
#define BKt 16
__global__ __launch_bounds__(256) void gemm_bias(const float* __restrict__ A,
                                                 const float* __restrict__ W,
                                                 const float* __restrict__ bias,
                                                 float* __restrict__ Cmat,
                                                 int M, int N, int K, int relu) {
    __shared__ float As[BKt][BM];
    __shared__ float Bs[BKt][BN];
    const int bm = blockIdx.y * BM;
    const int bn = blockIdx.x * BN;
    const int tid = threadIdx.x;
    const int tr = (tid >> 4) << 2;
    const int tc = (tid & 15) << 2;
    float acc[4][4] = {};

    const int lrow = tid >> 2;
    const int lc4  = (tid & 3) << 2;
    const float* Aptr = A + (size_t)(bm + lrow) * K + lc4;
    const float* Wptr = W + (size_t)(bn + lrow) * K + lc4;

    for (int k0 = 0; k0 < K; k0 += BKt) {
        float4 a4 = *(const float4*)(Aptr + k0);
        float4 w4 = *(const float4*)(Wptr + k0);
        As[lc4 + 0][lrow] = a4.x; As[lc4 + 1][lrow] = a4.y;
        As[lc4 + 2][lrow] = a4.z; As[lc4 + 3][lrow] = a4.w;
        Bs[lc4 + 0][lrow] = w4.x; Bs[lc4 + 1][lrow] = w4.y;
        Bs[lc4 + 2][lrow] = w4.z; Bs[lc4 + 3][lrow] = w4.w;
        __syncthreads();
#pragma unroll
        for (int kk = 0; kk < BKt; ++kk) {
            float a0 = As[kk][tr + 0], a1 = As[kk][tr + 1];
            float a2 = As[kk][tr + 2], a3 = As[kk][tr + 3];
            float b0 = Bs[kk][tc + 0], b1 = Bs[kk][tc + 1];
            float b2 = Bs[kk][tc + 2], b3 = Bs[kk][tc + 3];
            acc[0][0] = fmaf(a0, b0, acc[0][0]); acc[0][1] = fmaf(a0, b1, acc[0][1]);
            acc[0][2] = fmaf(a0, b2, acc[0][2]); acc[0][3] = fmaf(a0, b3, acc[0][3]);
            acc[1][0] = fmaf(a1, b0, acc[1][0]); acc[1][1] = fmaf(a1, b1, acc[1][1]);
            acc[1][2] = fmaf(a1, b2, acc[1][2]); acc[1][3] = fmaf(a1, b3, acc[1][3]);
            acc[2][0] = fmaf(a2, b0, acc[2][0]); acc[2][1] = fmaf(a2, b1, acc[2][1]);
            acc[2][2] = fmaf(a2, b2, acc[2][2]); acc[2][3] = fmaf(a2, b3, acc[2][3]);
            acc[3][0] = fmaf(a3, b0, acc[3][0]); acc[3][1] = fmaf(a3, b1, acc[3][1]);
            acc[3][2] = fmaf(a3, b2, acc[3][2]); acc[3][3] = fmaf(a3, b3, acc[3][3]);
        }
        __syncthreads();
    }
#pragma unroll
    for (int i = 0; i < 4; ++i) {
#pragma unroll
        for (int j = 0; j < 4; ++j) {
            float v = acc[i][j] + bias[bn + tc + j];
            if (relu) v = fmaxf(v, 0.f);
            Cmat[(size_t)(bm + tr + i) * N + bn + tc + j] = v;
        }
    }
}

// ---------------------------------------------------------------------------
// MFMA flash self-attention. grid (LQ/64, H, B), block 256 = 4 waves.
// Wave w owns keys [w*256, w*256+256) for the block's 64 queries.
// S^T = K·Q^T per 64-key tile (row=key, col=query in C-layout), online
// softmax with column reductions (in-lane + shfl_xor 16/32), P stored
// transposed to LDS as Ps[q][key] (packed b64 writes -> b128 A-frag reads),
// O += P·V with V staged transposed (Vt[d][key]). No barriers in K-loop
// (per-wave private LDS regions). 4 partial states merged at the end.
#define ATT_SCALE 0.17677669529663687f
__global__ __launch_bounds__(256, 2) void attn_mfma(const float* __restrict__ Q,
                                                    const float* __restrict__ Kb,
                                                    const float* __restrict__ Vb,
                                                    float* __restrict__ O) {
    const int b = blockIdx.z, h = blockIdx.y, qt = blockIdx.x;
    const int tid = threadIdx.x;
    const int wid = tid >> 6, lane = tid & 63;
    const int col16 = lane & 15, quad = lane >> 4;

    // 81920 B total. Per-wave region (ushorts): Ks[64][40]=2560, Vt[32][72]=2304,
    // Ps[64][72]=4608, corr 64 floats=128  => 9600/wave. Qs[64][40] at 4*9600.
    __shared__ unsigned short smem_us[40960];
    unsigned short* Ks = smem_us + wid * 9600;
    unsigned short* Vt = Ks + 2560;
    unsigned short* Ps = Ks + 4864;
    float* corr_s = (float*)(Ks + 9472);
    unsigned short* Qs = smem_us + 38400;

    // ---- stage Q (scaled by 1/sqrt(DH)) once, whole block
    {
        const int row = tid >> 2, part = tid & 3;
        const float* qsrc = Q + ((size_t)(b * LQv + qt * 64 + row)) * Cv + h * DHv + part * 8;
        float4 qa = *(const float4*)qsrc;
        float4 qb2 = *(const float4*)(qsrc + 4);
        uint4 qp = {pk_bf16x2(qa.x * ATT_SCALE, qa.y * ATT_SCALE),
                    pk_bf16x2(qa.z * ATT_SCALE, qa.w * ATT_SCALE),
                    pk_bf16x2(qb2.x * ATT_SCALE, qb2.y * ATT_SCALE),
                    pk_bf16x2(qb2.z * ATT_SCALE, qb2.w * ATT_SCALE)};
        *(uint4*)&Qs[row * 40 + part * 8] = qp;
    }
    __syncthreads();
    bhalf8 qfr[4];
#pragma unroll
    for (int j = 0; j < 4; ++j)
        qfr[j] = *(const bhalf8*)&Qs[(j * 16 + col16) * 40 + quad * 8];

    float m_state[4] = {-1e30f, -1e30f, -1e30f, -1e30f};
    float l_state[4] = {0.f, 0.f, 0.f, 0.f};
    floatx4 acc_o[4][2] = {};
    const int dd = lane & 31, half = lane >> 5;

    const float* kbase = Kb + ((size_t)(b * LQv + wid * 256)) * Cv + h * DHv;
    const float* vbase = Vb + ((size_t)(b * LQv + wid * 256)) * Cv + h * DHv;

#pragma unroll 1
    for (int t = 0; t < 4; ++t) {
        // ---- stage K tile [64 keys][32 d], lane = key
        {
            const float* ks = kbase + (size_t)(t * 64 + lane) * Cv;
            float4 f0 = *(const float4*)(ks + 0),  f1 = *(const float4*)(ks + 4);
            float4 f2 = *(const float4*)(ks + 8),  f3 = *(const float4*)(ks + 12);
            float4 f4 = *(const float4*)(ks + 16), f5 = *(const float4*)(ks + 20);
            float4 f6 = *(const float4*)(ks + 24), f7 = *(const float4*)(ks + 28);
            uint4 p0 = {pk_bf16x2(f0.x, f0.y), pk_bf16x2(f0.z, f0.w),
                        pk_bf16x2(f1.x, f1.y), pk_bf16x2(f1.z, f1.w)};
            uint4 p1 = {pk_bf16x2(f2.x, f2.y), pk_bf16x2(f2.z, f2.w),
                        pk_bf16x2(f3.x, f3.y), pk_bf16x2(f3.z, f3.w)};
            uint4 p2 = {pk_bf16x2(f4.x, f4.y), pk_bf16x2(f4.z, f4.w),
                        pk_bf16x2(f5.x, f5.y), pk_bf16x2(f5.z, f5.w)};
            uint4 p3 = {pk_bf16x2(f6.x, f6.y), pk_bf16x2(f6.z, f6.w),
                        pk_bf16x2(f7.x, f7.y), pk_bf16x2(f7.z, f7.w)};
            *(uint4*)&Ks[lane * 40 + 0]  = p0;
            *(uint4*)&Ks[lane * 40 + 8]  = p1;
            *(uint4*)&Ks[lane * 40 + 16] = p2;
            *(uint4*)&Ks[lane * 40 + 24] = p3;
        }
        // ---- stage V tile transposed: Vt[d][key]; lane = (d, key-half)
        {
            const float* vs = vbase + (size_t)(t * 64 + half * 32) * Cv + dd;
#pragma unroll
            for (int j4 = 0; j4 < 8; ++j4) {
                float g0 = vs[(j4 * 4 + 0) * Cv], g1 = vs[(j4 * 4 + 1) * Cv];
                float g2 = vs[(j4 * 4 + 2) * Cv], g3 = vs[(j4 * 4 + 3) * Cv];
                uint2 vp = {pk_bf16x2(g0, g1), pk_bf16x2(g2, g3)};
                *(uint2*)&Vt[dd * 72 + half * 32 + j4 * 4] = vp;
            }
        }

        // ---- S^T = K·Q^T : D[key, q]
        floatx4 accs[4][4] = {};   // [kf][qf]
        bhalf8 af[4];
#pragma unroll
        for (int kf = 0; kf < 4; ++kf)
            af[kf] = *(const bhalf8*)&Ks[(kf * 16 + col16) * 40 + quad * 8];
#pragma unroll
        for (int kf = 0; kf < 4; ++kf)
#pragma unroll
            for (int qf = 0; qf < 4; ++qf)
                accs[kf][qf] = __builtin_amdgcn_mfma_f32_16x16x32_bf16(
                    af[kf], qfr[qf], accs[kf][qf], 0, 0, 0);

        // ---- online softmax (per query column) + P store (transposed)
#pragma unroll
        for (int qf = 0; qf < 4; ++qf) {
            float tmax = -1e30f;
#pragma unroll
            for (int kf = 0; kf < 4; ++kf) {
                tmax = fmaxf(tmax, fmaxf(fmaxf(accs[kf][qf][0], accs[kf][qf][1]),
                                         fmaxf(accs[kf][qf][2], accs[kf][qf][3])));
            }
            tmax = fmaxf(tmax, __shfl_xor(tmax, 16));
            tmax = fmaxf(tmax, __shfl_xor(tmax, 32));
            float mnew = fmaxf(m_state[qf], tmax);
            float cr = __expf(m_state[qf] - mnew);
            m_state[qf] = mnew;
            float psum = 0.f;
#pragma unroll
            for (int kf = 0; kf < 4; ++kf) {
                float p0 = __expf(accs[kf][qf][0] - mnew);
                float p1 = __expf(accs[kf][qf][1] - mnew);
                float p2 = __expf(accs[kf][qf][2] - mnew);
                float p3 = __expf(accs[kf][qf][3] - mnew);
                psum += (p0 + p1) + (p2 + p3);
                uint2 pp = {pk_bf16x2(p0, p1), pk_bf16x2(p2, p3)};
                *(uint2*)&Ps[(qf * 16 + col16) * 72 + kf * 16 + quad * 4] = pp;
            }
            psum += __shfl_xor(psum, 16);
            psum += __shfl_xor(psum, 32);
            l_state[qf] = l_state[qf] * cr + psum;
            if (quad == 0) corr_s[qf * 16 + col16] = cr;
        }

        // ---- rescale O accumulator by corr (per D-layout row q)
#pragma unroll
        for (int mf = 0; mf < 4; ++mf) {
            float4 cv = *(const float4*)&corr_s[mf * 16 + quad * 4];
#pragma unroll
            for (int nf = 0; nf < 2; ++nf) {
                acc_o[mf][nf][0] *= cv.x;
                acc_o[mf][nf][1] *= cv.y;
                acc_o[mf][nf][2] *= cv.z;
                acc_o[mf][nf][3] *= cv.w;
            }
        }
        // ---- O += P·V  (k = 64 keys, 2 mfma k-steps)
#pragma unroll
        for (int ks2 = 0; ks2 < 2; ++ks2) {
            bhalf8 pf[4], vf[2];
#pragma unroll
            for (int mf = 0; mf < 4; ++mf)
                pf[mf] = *(const bhalf8*)&Ps[(mf * 16 + col16) * 72 + ks2 * 32 + quad * 8];
#pragma unroll
            for (int nf = 0; nf < 2; ++nf)
                vf[nf] = *(const bhalf8*)&Vt[(nf * 16 + col16) * 72 + ks2 * 32 + quad * 8];
#pragma unroll
            for (int mf = 0; mf < 4; ++mf)
#pragma unroll
                for (int nf = 0; nf < 2; ++nf)
                    acc_o[mf][nf] = __builtin_amdgcn_mfma_f32_16x16x32_bf16(
                        pf[mf], vf[nf], acc_o[mf][nf], 0, 0, 0);
        }
    }

    // ---- merge the 4 per-wave partial states (alias LDS after barrier)
    __syncthreads();
    float* mbuf = (float*)smem_us;          // [4][64]
    float* lbuf = mbuf + 256;               // [4][64]
    float* obuf = lbuf + 256;               // [4][64][32]
    if (quad == 0) {
#pragma unroll
        for (int qf = 0; qf < 4; ++qf) {
            mbuf[wid * 64 + qf * 16 + col16] = m_state[qf];
            lbuf[wid * 64 + qf * 16 + col16] = l_state[qf];
        }
    }
#pragma unroll
    for (int mf = 0; mf < 4; ++mf)
#pragma unroll
        for (int nf = 0; nf < 2; ++nf)
#pragma unroll
            for (int i = 0; i < 4; ++i)
                obuf[wid * 2048 + (mf * 16 + quad * 4 + i) * 32 + nf * 16 + col16] =
                    acc_o[mf][nf][i];
    __syncthreads();
    {
        const int q = tid >> 2, dg = (tid & 3) * 8;
        float m0 = mbuf[q], m1 = mbuf[64 + q], m2 = mbuf[128 + q], m3 = mbuf[192 + q];
        float gm = fmaxf(fmaxf(m0, m1), fmaxf(m2, m3));
        float e0 = __expf(m0 - gm), e1 = __expf(m1 - gm);
        float e2 = __expf(m2 - gm), e3 = __expf(m3 - gm);
        float lt = lbuf[q] * e0 + lbuf[64 + q] * e1 + lbuf[128 + q] * e2 + lbuf[192 + q] * e3;
        float inv = 1.f / lt;
        const float* o0 = obuf + q * 32 + dg;
        float* orow = O + ((size_t)(b * LQv + qt * 64 + q)) * Cv + h * DHv + dg;
        float ov[8];
#pragma unroll
        for (int d = 0; d < 8; ++d)
            ov[d] = (o0[d] * e0 + o0[2048 + d] * e1 + o0[4096 + d] * e2 + o0[6144 + d] * e3) * inv;
        *(float4*)(orow) = make_float4(ov[0], ov[1], ov[2], ov[3]);
        *(float4*)(orow + 4) = make_float4(ov[4], ov[5], ov[6], ov[7]);
    }
}

// ---------------------------------------------------------------------------
// Deformable sampling. grid: B*LQ blocks, 256 threads: thread = (h, d).
__global__ __launch_bounds__(256) void deform_sample(const float* __restrict__ value,
                                                     const float* __restrict__ offs,
                                                     const float* __restrict__ awl,
                                                     const float* __restrict__ ref,
                                                     float* __restrict__ out) {
    const int bq = blockIdx.x;          // b*LQ + q
    const int b = bq >> 10;
    const int tid = threadIdx.x;
    const int h = tid >> 5, d = tid & 31;

    const float* aw = awl + (size_t)bq * (Hv * Lv * Pv) + h * 16;
    float w[16];
    float mx = -1e30f;
#pragma unroll
    for (int j = 0; j < 16; ++j) { w[j] = aw[j]; mx = fmaxf(mx, w[j]); }
    float ssum = 0.f;
#pragma unroll
    for (int j = 0; j < 16; ++j) { w[j] = __expf(w[j] - mx); ssum += w[j]; }
    float invs = 1.f / ssum;

    const float* op = offs + (size_t)bq * 256 + h * 32;
    const float* rp = ref + (size_t)bq * (Lv * 2);

    const int starts[4] = {0, 16384, 20480, 21504};
    const int WHl[4] = {128, 64, 32, 16};

    float acc = 0.f;
#pragma unroll 1
    for (int l = 0; l < 4; ++l) {
        const int wl = WHl[l];
        const float rx = rp[l * 2 + 0], ry = rp[l * 2 + 1];
        const float* vbase = value + ((size_t)b * LSRCv + starts[l]) * Cv + h * DHv + d;
#pragma unroll 1
        for (int p = 0; p < 4; ++p) {
            float ox = op[l * 8 + p * 2 + 0], oy = op[l * 8 + p * 2 + 1];
            float x = rx * (float)wl + ox - 0.5f;
            float y = ry * (float)wl + oy - 0.5f;
            float fx0 = floorf(x), fy0 = floorf(y);
            int x0 = (int)fx0, y0 = (int)fy0;
            float tx = x - fx0, ty = y - fy0;
            float w00 = (1.f - tx) * (1.f - ty);
            float w10 = tx * (1.f - ty);
            float w01 = (1.f - tx) * ty;
            float w11 = tx * ty;
            float s = 0.f;
            bool xin0 = (x0 >= 0) & (x0 < wl);
            bool xin1 = (x0 + 1 >= 0) & (x0 + 1 < wl);
            bool yin0 = (y0 >= 0) & (y0 < wl);
            bool yin1 = (y0 + 1 >= 0) & (y0 + 1 < wl);
            if (yin0) {
                if (xin0) s = fmaf(w00, vbase[(size_t)(y0 * wl + x0) * Cv], s);
                if (xin1) s = fmaf(w10, vbase[(size_t)(y0 * wl + x0 + 1) * Cv], s);
            }
            if (yin1) {
                if (xin0) s = fmaf(w01, vbase[(size_t)((y0 + 1) * wl + x0) * Cv], s);
                if (xin1) s = fmaf(w11, vbase[(size_t)((y0 + 1) * wl + x0 + 1) * Cv], s);
            }
            acc = fmaf(w[l * 4 + p] * invs, s, acc);
        }
    }
    out[(size_t)bq * Cv + h * DHv + d] = acc;
}

// ---------------------------------------------------------------------------
// out = LayerNorm(x + r) * g + b    one block per row of 256
__global__ __launch_bounds__(256) void ln_residual(const float* __restrict__ x,
                                                   const float* __restrict__ r,
                                                   const float* __restrict__ g,
                                                   const float* __restrict__ bta,
                                                   float* __restrict__ out) {
    const int row = blockIdx.x;
    const int tid = threadIdx.x;
    float v = x[(size_t)row * Cv + tid] + r[(size_t)row * Cv + tid];
    float s = v, sq = v * v;
#pragma unroll
    for (int off = 32; off > 0; off >>= 1) {
        s  += __shfl_down(s, off, 64);
        sq += __shfl_down(sq, off, 64);
    }
    __shared__ float ss[4], sqq[4];
    int wid = tid >> 6;
    if ((tid & 63) == 0) { ss[wid] = s; sqq[wid] = sq; }
    __syncthreads();
    __shared__ float meansh, rstdsh;
    if (tid == 0) {
        float S = ss[0] + ss[1] + ss[2] + ss[3];
        float Q = sqq[0] + sqq[1] + sqq[2] + sqq[3];
        float mean = S * (1.f / Cv);
        float var = Q * (1.f / Cv) - mean * mean;
        meansh = mean;
        rstdsh = rsqrtf(var + 1e-5f);
    }
    __syncthreads();
    out[(size_t)row * Cv + tid] = (v - meansh) * rstdsh * g[tid] + bta[tid];
}

// ---------------------------------------------------------------------------
extern "C" void kernel_launch(void* const* d_in, const int* in_sizes, int n_in,
                              void* d_out, int out_size, void* d_ws, size_t ws_size,
                              hipStream_t stream) {
    const float* tgt       = (const float*)d_in[0];
    const float* query_pos = (const float*)d_in[1];
    const float* ref_pts   = (const float*)d_in[2];
    const float* src       = (const float*)d_in[3];
    const float* in_w      = (const float*)d_in[4];
    const float* in_b      = (const float*)d_in[5];
    const float* sa_w      = (const float*)d_in[6];
    const float* sa_b      = (const float*)d_in[7];
    const float* off_w     = (const float*)d_in[8];
    const float* off_b     = (const float*)d_in[9];
    const float* aw_w      = (const float*)d_in[10];
    const float* aw_b      = (const float*)d_in[11];
    const float* val_w     = (const float*)d_in[12];
    const float* val_b     = (const float*)d_in[13];
    const float* co_w      = (const float*)d_in[14];
    const float* co_b      = (const float*)d_in[15];
    const float* ln1_g     = (const float*)d_in[16];
    const float* ln1_b     = (const float*)d_in[17];
    const float* ln2_g     = (const float*)d_in[18];
    const float* ln2_b     = (const float*)d_in[19];
    const float* ln3_g     = (const float*)d_in[20];
    const float* ln3_b     = (const float*)d_in[21];
    const float* f1_w      = (const float*)d_in[22];
    const float* f1_b      = (const float*)d_in[23];
    const float* f2_w      = (const float*)d_in[24];
    const float* f2_b      = (const float*)d_in[25];

    const int M0  = Bv * LQv * Cv;          // 1048576
    const int VSZ = Bv * LSRCv * Cv;        // 22282240
    float* ws = (float*)d_ws;

    // Phase-A buffers alias the (later) value region — lifetimes don't overlap.
    float* big    = ws;                     // VSZ floats
    float* qk     = big;
    float* qb     = big + (size_t)M0;
    float* kb     = big + (size_t)2 * M0;
    float* vb     = big + (size_t)3 * M0;
    float* ob     = big + (size_t)4 * M0;
    float* value  = big;
    float* tgt_a  = ws + (size_t)VSZ;
    float* query  = tgt_a + M0;
    float* offs   = query + M0;
    float* awb    = offs + M0;              // B*LQ*128
    float* sampled= awb + (size_t)Bv * LQv * 128;
    float* tgt_b  = sampled + M0;
    float* hidden = tgt_b + M0;             // B*LQ*DFF
    float* tmp    = hidden + (size_t)Bv * LQv * DFFv;

    const int Mq = Bv * LQv;                // 4096 rows
    dim3 blk256(256);

    // 1. qk = tgt + query_pos
    add_kernel<<<dim3(M0 / 4 / 256), blk256, 0, stream>>>(tgt, query_pos, qk, M0 / 4);

    // 2. q,k,v projections (bf16 MFMA)
    gemm_mfma<<<dim3(Cv / 128, Mq / 128), blk256, 0, stream>>>(qk, in_w,                    in_b,       qb, Mq, Cv, Cv, 0);
    gemm_mfma<<<dim3(Cv / 128, Mq / 128), blk256, 0, stream>>>(qk, in_w + (size_t)Cv * Cv,  in_b + Cv,  kb, Mq, Cv, Cv, 0);
    gemm_mfma<<<dim3(Cv / 128, Mq / 128), blk256, 0, stream>>>(tgt, in_w + (size_t)2*Cv*Cv, in_b + 2*Cv, vb, Mq, Cv, Cv, 0);

    // 3. self-attention (MFMA flash, 4-wave key-split)
    attn_mfma<<<dim3(LQv / 64, Hv, Bv), blk256, 0, stream>>>(qb, kb, vb, ob);

    // 4. output projection, 5. LN2 residual
    gemm_mfma<<<dim3(Cv / 128, Mq / 128), blk256, 0, stream>>>(ob, sa_w, sa_b, tmp, Mq, Cv, Cv, 0);
    ln_residual<<<dim3(Mq), blk256, 0, stream>>>(tgt, tmp, ln2_g, ln2_b, tgt_a);

    // 6. query = tgt_a + query_pos
    add_kernel<<<dim3(M0 / 4 / 256), blk256, 0, stream>>>(tgt_a, query_pos, query, M0 / 4);

    // 7. value projection (the big GEMM, bf16 MFMA)
    gemm_mfma<<<dim3(Cv / 128, (Bv * LSRCv) / 128), blk256, 0, stream>>>(src, val_w, val_b, value, Bv * LSRCv, Cv, Cv, 0);

    // 8. offsets (fp32 — sampling-location precision), 9. aw logits (bf16)
    gemm_bias<<<dim3(Cv / BN, Mq / BM), blk256, 0, stream>>>(query, off_w, off_b, offs, Mq, Cv, Cv, 0);
    gemm_mfma<<<dim3(128 / 128, Mq / 128), blk256, 0, stream>>>(query, aw_w, aw_b, awb, Mq, 128, Cv, 0);

    // 10. deformable bilinear sampling
    deform_sample<<<dim3(Bv * LQv), blk256, 0, stream>>>(value, offs, awb, ref_pts, sampled);

    // 11. cross-attn output projection, 12. LN1 residual
    gemm_mfma<<<dim3(Cv / 128, Mq / 128), blk256, 0, stream>>>(sampled, co_w, co_b, tmp, Mq, Cv, Cv, 0);
    ln_residual<<<dim3(Mq), blk256, 0, stream>>>(tgt_a, tmp, ln1_g, ln1_b, tgt_b);

    // 13./14. FFN (bf16 MFMA), 15. LN3 → d_out
    gemm_mfma<<<dim3(DFFv / 128, Mq / 128), blk256, 0, stream>>>(tgt_b, f1_w, f1_b, hidden, Mq, DFFv, Cv, 1);
    gemm_mfma<<<dim3(Cv / 128, Mq / 128), blk256, 0, stream>>>(hidden, f2_w, f2_b, tmp, Mq, Cv, DFFv, 0);
    ln_residual<<<dim3(Mq), blk256, 0, stream>>>(tgt_b, tmp, ln3_g, ln3_b, (float*)d_out);
}

// Round 6
// 472.627 us; speedup vs baseline: 11.6972x; 1.0569x over previous
//
#include <hip/hip_runtime.h>
#include <hip/hip_bf16.h>
#include <math.h>

// Problem constants
#define Bv   4
#define LQv  1024
#define Cv   256
#define Hv   8
#define Lv   4
#define Pv   4
#define DFFv 1024
#define DHv  32
#define LSRCv 21760   // 128*128 + 64*64 + 32*32 + 16*16

typedef __attribute__((ext_vector_type(8))) short bhalf8;   // 8 bf16 (4 VGPRs)
typedef __attribute__((ext_vector_type(4))) float floatx4;  // MFMA acc

// fp32 -> bf16 RNE, packed pair
__device__ inline unsigned pk_bf16x2(float x, float y) {
    unsigned xb = __float_as_uint(x), yb = __float_as_uint(y);
    unsigned xr = (xb + 0x7FFFu + ((xb >> 16) & 1u)) >> 16;
    unsigned yr = (yb + 0x7FFFu + ((yb >> 16) & 1u)) >> 16;
    return xr | (yr << 16);
}
__device__ inline unsigned short bf16_1(float x) {
    unsigned xb = __float_as_uint(x);
    return (unsigned short)((xb + 0x7FFFu + ((xb >> 16) & 1u)) >> 16);
}
__device__ inline float ubf2f(unsigned short u) {
    return __uint_as_float(((unsigned)u) << 16);
}

// ---------------------------------------------------------------------------
// bf16-MFMA GEMM v2: C[M,N] = (A[+A2])[M,K] @ W[N,K]^T + bias[N].
// - optional fused residual add (A2 != nullptr)
// - optional bf16 output (Ch != nullptr, else Cf)
// - register double-buffer prefetch of next K-tile (overlaps MFMA compute)
// - LDS rows padded to 40 ushorts (20-bank stride -> 2-way aliasing, free)
// 128x128 tile, BK=32, 256 thr = 4 waves. M%128==0, N%128==0, K%32==0.
__global__ __launch_bounds__(256) void gemm_mfma(const float* __restrict__ A,
                                                 const float* __restrict__ A2,
                                                 const float* __restrict__ W,
                                                 const float* __restrict__ bias,
                                                 float* __restrict__ Cf,
                                                 unsigned short* __restrict__ Ch,
                                                 int M, int N, int K, int relu) {
    __shared__ unsigned short As[128 * 40];
    __shared__ unsigned short Bs[128 * 40];
    const int bm = blockIdx.y * 128;
    const int bn = blockIdx.x * 128;
    const int tid = threadIdx.x;
    const int wid = tid >> 6, lane = tid & 63;
    const int wm = (wid >> 1) * 64, wn = (wid & 1) * 64;
    const int col16 = lane & 15;
    const int quad = lane >> 4;

    const int r = tid >> 1;           // staging row 0..127
    const int half = tid & 1;         // k-half (16 floats)
    const float* aptr = A + (size_t)(bm + r) * K + (half << 4);
    const float* a2ptr = A2 ? A2 + (size_t)(bm + r) * K + (half << 4) : nullptr;
    const float* wptr = W + (size_t)(bn + r) * K + (half << 4);
    unsigned* as_dst = (unsigned*)As + r * 20 + (half << 3);
    unsigned* bs_dst = (unsigned*)Bs + r * 20 + (half << 3);

    float4 av[4], wv[4];
    auto ldtile = [&](int kc) {
        const float4* ap = (const float4*)(aptr + kc);
        const float4* wp = (const float4*)(wptr + kc);
#pragma unroll
        for (int i = 0; i < 4; ++i) { av[i] = ap[i]; wv[i] = wp[i]; }
        if (a2ptr) {
            const float4* p2 = (const float4*)(a2ptr + kc);
#pragma unroll
            for (int i = 0; i < 4; ++i) {
                float4 t = p2[i];
                av[i].x += t.x; av[i].y += t.y; av[i].z += t.z; av[i].w += t.w;
            }
        }
    };

    floatx4 acc[4][4] = {};
    ldtile(0);

    for (int kc = 0; kc < K; kc += 32) {
        uint4 au0 = {pk_bf16x2(av[0].x, av[0].y), pk_bf16x2(av[0].z, av[0].w),
                     pk_bf16x2(av[1].x, av[1].y), pk_bf16x2(av[1].z, av[1].w)};
        uint4 au1 = {pk_bf16x2(av[2].x, av[2].y), pk_bf16x2(av[2].z, av[2].w),
                     pk_bf16x2(av[3].x, av[3].y), pk_bf16x2(av[3].z, av[3].w)};
        uint4 wu0 = {pk_bf16x2(wv[0].x, wv[0].y), pk_bf16x2(wv[0].z, wv[0].w),
                     pk_bf16x2(wv[1].x, wv[1].y), pk_bf16x2(wv[1].z, wv[1].w)};
        uint4 wu1 = {pk_bf16x2(wv[2].x, wv[2].y), pk_bf16x2(wv[2].z, wv[2].w),
                     pk_bf16x2(wv[3].x, wv[3].y), pk_bf16x2(wv[3].z, wv[3].w)};
        *(uint4*)as_dst = au0;
        *(uint4*)(as_dst + 4) = au1;
        *(uint4*)bs_dst = wu0;
        *(uint4*)(bs_dst + 4) = wu1;
        if (kc + 32 < K) ldtile(kc + 32);   // prefetch in flight over MFMA block
        __syncthreads();

        bhalf8 af[4], bf[4];
#pragma unroll
        for (int mt = 0; mt < 4; ++mt)
            af[mt] = *(const bhalf8*)&As[(wm + mt * 16 + col16) * 40 + quad * 8];
#pragma unroll
        for (int nt = 0; nt < 4; ++nt)
            bf[nt] = *(const bhalf8*)&Bs[(wn + nt * 16 + col16) * 40 + quad * 8];
#pragma unroll
        for (int mt = 0; mt < 4; ++mt)
#pragma unroll
            for (int nt = 0; nt < 4; ++nt)
                acc[mt][nt] = __builtin_amdgcn_mfma_f32_16x16x32_bf16(
                    af[mt], bf[nt], acc[mt][nt], 0, 0, 0);
        __syncthreads();
    }

#pragma unroll
    for (int mt = 0; mt < 4; ++mt) {
#pragma unroll
        for (int nt = 0; nt < 4; ++nt) {
            const int col = bn + wn + nt * 16 + col16;
            const float bv = bias[col];
#pragma unroll
            for (int i = 0; i < 4; ++i) {
                const int row = bm + wm + mt * 16 + quad * 4 + i;
                float v = acc[mt][nt][i] + bv;
                if (relu) v = fmaxf(v, 0.f);
                if (Ch) Ch[(size_t)row * N + col] = bf16_1(v);
                else    Cf[(size_t)row * N + col] = v;
            }
        }
    }
}

// ---------------------------------------------------------------------------
// MFMA flash self-attention. grid (LQ/64, H, B), block 256 = 4 waves.
// Q/K read with configurable row stride (they live in one [M,512] buffer).
#define ATT_SCALE 0.17677669529663687f
__global__ __launch_bounds__(256, 2) void attn_mfma(const float* __restrict__ Q,
                                                    const float* __restrict__ Kb,
                                                    const float* __restrict__ Vb,
                                                    float* __restrict__ O,
                                                    int qk_stride) {
    const int b = blockIdx.z, h = blockIdx.y, qt = blockIdx.x;
    const int tid = threadIdx.x;
    const int wid = tid >> 6, lane = tid & 63;
    const int col16 = lane & 15, quad = lane >> 4;

    __shared__ unsigned short smem_us[40960];
    unsigned short* Ks = smem_us + wid * 9600;
    unsigned short* Vt = Ks + 2560;
    unsigned short* Ps = Ks + 4864;
    float* corr_s = (float*)(Ks + 9472);
    unsigned short* Qs = smem_us + 38400;

    // ---- stage Q (scaled) once, whole block
    {
        const int row = tid >> 2, part = tid & 3;
        const float* qsrc = Q + ((size_t)(b * LQv + qt * 64 + row)) * qk_stride + h * DHv + part * 8;
        float4 qa = *(const float4*)qsrc;
        float4 qb2 = *(const float4*)(qsrc + 4);
        uint4 qp = {pk_bf16x2(qa.x * ATT_SCALE, qa.y * ATT_SCALE),
                    pk_bf16x2(qa.z * ATT_SCALE, qa.w * ATT_SCALE),
                    pk_bf16x2(qb2.x * ATT_SCALE, qb2.y * ATT_SCALE),
                    pk_bf16x2(qb2.z * ATT_SCALE, qb2.w * ATT_SCALE)};
        *(uint4*)&Qs[row * 40 + part * 8] = qp;
    }
    __syncthreads();
    bhalf8 qfr[4];
#pragma unroll
    for (int j = 0; j < 4; ++j)
        qfr[j] = *(const bhalf8*)&Qs[(j * 16 + col16) * 40 + quad * 8];

    float m_state[4] = {-1e30f, -1e30f, -1e30f, -1e30f};
    float l_state[4] = {0.f, 0.f, 0.f, 0.f};
    floatx4 acc_o[4][2] = {};
    const int dd = lane & 31, half = lane >> 5;

    const float* kbase = Kb + ((size_t)(b * LQv + wid * 256)) * qk_stride + h * DHv;
    const float* vbase = Vb + ((size_t)(b * LQv + wid * 256)) * Cv + h * DHv;

#pragma unroll 1
    for (int t = 0; t < 4; ++t) {
        {
            const float* ks = kbase + (size_t)(t * 64 + lane) * qk_stride;
            float4 f0 = *(const float4*)(ks + 0),  f1 = *(const float4*)(ks + 4);
            float4 f2 = *(const float4*)(ks + 8),  f3 = *(const float4*)(ks + 12);
            float4 f4 = *(const float4*)(ks + 16), f5 = *(const float4*)(ks + 20);
            float4 f6 = *(const float4*)(ks + 24), f7 = *(const float4*)(ks + 28);
            uint4 p0 = {pk_bf16x2(f0.x, f0.y), pk_bf16x2(f0.z, f0.w),
                        pk_bf16x2(f1.x, f1.y), pk_bf16x2(f1.z, f1.w)};
            uint4 p1 = {pk_bf16x2(f2.x, f2.y), pk_bf16x2(f2.z, f2.w),
                        pk_bf16x2(f3.x, f3.y), pk_bf16x2(f3.z, f3.w)};
            uint4 p2 = {pk_bf16x2(f4.x, f4.y), pk_bf16x2(f4.z, f4.w),
                        pk_bf16x2(f5.x, f5.y), pk_bf16x2(f5.z, f5.w)};
            uint4 p3 = {pk_bf16x2(f6.x, f6.y), pk_bf16x2(f6.z, f6.w),
                        pk_bf16x2(f7.x, f7.y), pk_bf16x2(f7.z, f7.w)};
            *(uint4*)&Ks[lane * 40 + 0]  = p0;
            *(uint4*)&Ks[lane * 40 + 8]  = p1;
            *(uint4*)&Ks[lane * 40 + 16] = p2;
            *(uint4*)&Ks[lane * 40 + 24] = p3;
        }
        {
            const float* vs = vbase + (size_t)(t * 64 + half * 32) * Cv + dd;
#pragma unroll
            for (int j4 = 0; j4 < 8; ++j4) {
                float g0 = vs[(j4 * 4 + 0) * Cv], g1 = vs[(j4 * 4 + 1) * Cv];
                float g2 = vs[(j4 * 4 + 2) * Cv], g3 = vs[(j4 * 4 + 3) * Cv];
                uint2 vp = {pk_bf16x2(g0, g1), pk_bf16x2(g2, g3)};
                *(uint2*)&Vt[dd * 72 + half * 32 + j4 * 4] = vp;
            }
        }

        floatx4 accs[4][4] = {};
        bhalf8 af[4];
#pragma unroll
        for (int kf = 0; kf < 4; ++kf)
            af[kf] = *(const bhalf8*)&Ks[(kf * 16 + col16) * 40 + quad * 8];
#pragma unroll
        for (int kf = 0; kf < 4; ++kf)
#pragma unroll
            for (int qf = 0; qf < 4; ++qf)
                accs[kf][qf] = __builtin_amdgcn_mfma_f32_16x16x32_bf16(
                    af[kf], qfr[qf], accs[kf][qf], 0, 0, 0);

#pragma unroll
        for (int qf = 0; qf < 4; ++qf) {
            float tmax = -1e30f;
#pragma unroll
            for (int kf = 0; kf < 4; ++kf) {
                tmax = fmaxf(tmax, fmaxf(fmaxf(accs[kf][qf][0], accs[kf][qf][1]),
                                         fmaxf(accs[kf][qf][2], accs[kf][qf][3])));
            }
            tmax = fmaxf(tmax, __shfl_xor(tmax, 16));
            tmax = fmaxf(tmax, __shfl_xor(tmax, 32));
            float mnew = fmaxf(m_state[qf], tmax);
            float cr = __expf(m_state[qf] - mnew);
            m_state[qf] = mnew;
            float psum = 0.f;
#pragma unroll
            for (int kf = 0; kf < 4; ++kf) {
                float p0 = __expf(accs[kf][qf][0] - mnew);
                float p1 = __expf(accs[kf][qf][1] - mnew);
                float p2 = __expf(accs[kf][qf][2] - mnew);
                float p3 = __expf(accs[kf][qf][3] - mnew);
                psum += (p0 + p1) + (p2 + p3);
                uint2 pp = {pk_bf16x2(p0, p1), pk_bf16x2(p2, p3)};
                *(uint2*)&Ps[(qf * 16 + col16) * 72 + kf * 16 + quad * 4] = pp;
            }
            psum += __shfl_xor(psum, 16);
            psum += __shfl_xor(psum, 32);
            l_state[qf] = l_state[qf] * cr + psum;
            if (quad == 0) corr_s[qf * 16 + col16] = cr;
        }

#pragma unroll
        for (int mf = 0; mf < 4; ++mf) {
            float4 cv = *(const float4*)&corr_s[mf * 16 + quad * 4];
#pragma unroll
            for (int nf = 0; nf < 2; ++nf) {
                acc_o[mf][nf][0] *= cv.x;
                acc_o[mf][nf][1] *= cv.y;
                acc_o[mf][nf][2] *= cv.z;
                acc_o[mf][nf][3] *= cv.w;
            }
        }
#pragma unroll
        for (int ks2 = 0; ks2 < 2; ++ks2) {
            bhalf8 pf[4], vf[2];
#pragma unroll
            for (int mf = 0; mf < 4; ++mf)
                pf[mf] = *(const bhalf8*)&Ps[(mf * 16 + col16) * 72 + ks2 * 32 + quad * 8];
#pragma unroll
            for (int nf = 0; nf < 2; ++nf)
                vf[nf] = *(const bhalf8*)&Vt[(nf * 16 + col16) * 72 + ks2 * 32 + quad * 8];
#pragma unroll
            for (int mf = 0; mf < 4; ++mf)
#pragma unroll
                for (int nf = 0; nf < 2; ++nf)
                    acc_o[mf][nf] = __builtin_amdgcn_mfma_f32_16x16x32_bf16(
                        pf[mf], vf[nf], acc_o[mf][nf], 0, 0, 0);
        }
    }

    __syncthreads();
    float* mbuf = (float*)smem_us;
    float* lbuf = mbuf + 256;
    float* obuf = lbuf + 256;
    if (quad == 0) {
#pragma unroll
        for (int qf = 0; qf < 4; ++qf) {
            mbuf[wid * 64 + qf * 16 + col16] = m_state[qf];
            lbuf[wid * 64 + qf * 16 + col16] = l_state[qf];
        }
    }
#pragma unroll
    for (int mf = 0; mf < 4; ++mf)
#pragma unroll
        for (int nf = 0; nf < 2; ++nf)
#pragma unroll
            for (int i = 0; i < 4; ++i)
                obuf[wid * 2048 + (mf * 16 + quad * 4 + i) * 32 + nf * 16 + col16] =
                    acc_o[mf][nf][i];
    __syncthreads();
    {
        const int q = tid >> 2, dg = (tid & 3) * 8;
        float m0 = mbuf[q], m1 = mbuf[64 + q], m2 = mbuf[128 + q], m3 = mbuf[192 + q];
        float gm = fmaxf(fmaxf(m0, m1), fmaxf(m2, m3));
        float e0 = __expf(m0 - gm), e1 = __expf(m1 - gm);
        float e2 = __expf(m2 - gm), e3 = __expf(m3 - gm);
        float lt = lbuf[q] * e0 + lbuf[64 + q] * e1 + lbuf[128 + q] * e2 + lbuf[192 + q] * e3;
        float inv = 1.f / lt;
        const float* o0 = obuf + q * 32 + dg;
        float* orow = O + ((size_t)(b * LQv + qt * 64 + q)) * Cv + h * DHv + dg;
        float ov[8];
#pragma unroll
        for (int d = 0; d < 8; ++d)
            ov[d] = (o0[d] * e0 + o0[2048 + d] * e1 + o0[4096 + d] * e2 + o0[6144 + d] * e3) * inv;
        *(float4*)(orow) = make_float4(ov[0], ov[1], ov[2], ov[3]);
        *(float4*)(orow + 4) = make_float4(ov[4], ov[5], ov[6], ov[7]);
    }
}

// ---------------------------------------------------------------------------
// Deformable sampling over bf16 value. grid: B*LQ blocks, 256 thr = (h, d).
__global__ __launch_bounds__(256) void deform_sample(const unsigned short* __restrict__ value,
                                                     const float* __restrict__ offs,
                                                     const float* __restrict__ awl,
                                                     const float* __restrict__ ref,
                                                     float* __restrict__ out) {
    const int bq = blockIdx.x;          // b*LQ + q
    const int b = bq >> 10;
    const int tid = threadIdx.x;
    const int h = tid >> 5, d = tid & 31;

    const float* aw = awl + (size_t)bq * (Hv * Lv * Pv) + h * 16;
    float w[16];
    float mx = -1e30f;
#pragma unroll
    for (int j = 0; j < 16; ++j) { w[j] = aw[j]; mx = fmaxf(mx, w[j]); }
    float ssum = 0.f;
#pragma unroll
    for (int j = 0; j < 16; ++j) { w[j] = __expf(w[j] - mx); ssum += w[j]; }
    float invs = 1.f / ssum;

    const float* op = offs + (size_t)bq * 256 + h * 32;
    const float* rp = ref + (size_t)bq * (Lv * 2);

    const int starts[4] = {0, 16384, 20480, 21504};
    const int WHl[4] = {128, 64, 32, 16};

    float acc = 0.f;
#pragma unroll 1
    for (int l = 0; l < 4; ++l) {
        const int wl = WHl[l];
        const float rx = rp[l * 2 + 0], ry = rp[l * 2 + 1];
        const unsigned short* vb0 = value + ((size_t)b * LSRCv + starts[l]) * Cv + h * DHv + d;
#pragma unroll 1
        for (int p = 0; p < 4; ++p) {
            float ox = op[l * 8 + p * 2 + 0], oy = op[l * 8 + p * 2 + 1];
            float x = rx * (float)wl + ox - 0.5f;
            float y = ry * (float)wl + oy - 0.5f;
            float fx0 = floorf(x), fy0 = floorf(y);
            int x0 = (int)fx0, y0 = (int)fy0;
            float tx = x - fx0, ty = y - fy0;
            float w00 = (1.f - tx) * (1.f - ty);
            float w10 = tx * (1.f - ty);
            float w01 = (1.f - tx) * ty;
            float w11 = tx * ty;
            float s = 0.f;
            bool xin0 = (x0 >= 0) & (x0 < wl);
            bool xin1 = (x0 + 1 >= 0) & (x0 + 1 < wl);
            bool yin0 = (y0 >= 0) & (y0 < wl);
            bool yin1 = (y0 + 1 >= 0) & (y0 + 1 < wl);
            if (yin0) {
                if (xin0) s = fmaf(w00, ubf2f(vb0[(size_t)(y0 * wl + x0) * Cv]), s);
                if (xin1) s = fmaf(w10, ubf2f(vb0[(size_t)(y0 * wl + x0 + 1) * Cv]), s);
            }
            if (yin1) {
                if (xin0) s = fmaf(w01, ubf2f(vb0[(size_t)((y0 + 1) * wl + x0) * Cv]), s);
                if (xin1) s = fmaf(w11, ubf2f(vb0[(size_t)((y0 + 1) * wl + x0 + 1) * Cv]), s);
            }
            acc = fmaf(w[l * 4 + p] * invs, s, acc);
        }
    }
    out[(size_t)bq * Cv + h * DHv + d] = acc;
}

// ---------------------------------------------------------------------------
// out = LayerNorm(x + r) * g + b    one block per row of 256
__global__ __launch_bounds__(256) void ln_residual(const float* __restrict__ x,
                                                   const float* __restrict__ r,
                                                   const float* __restrict__ g,
                                                   const float* __restrict__ bta,
                                                   float* __restrict__ out) {
    const int row = blockIdx.x;
    const int tid = threadIdx.x;
    float v = x[(size_t)row * Cv + tid] + r[(size_t)row * Cv + tid];
    float s = v, sq = v * v;
#pragma unroll
    for (int off = 32; off > 0; off >>= 1) {
        s  += __shfl_down(s, off, 64);
        sq += __shfl_down(sq, off, 64);
    }
    __shared__ float ss[4], sqq[4];
    int wid = tid >> 6;
    if ((tid & 63) == 0) { ss[wid] = s; sqq[wid] = sq; }
    __syncthreads();
    __shared__ float meansh, rstdsh;
    if (tid == 0) {
        float S = ss[0] + ss[1] + ss[2] + ss[3];
        float Q = sqq[0] + sqq[1] + sqq[2] + sqq[3];
        float mean = S * (1.f / Cv);
        float var = Q * (1.f / Cv) - mean * mean;
        meansh = mean;
        rstdsh = rsqrtf(var + 1e-5f);
    }
    __syncthreads();
    out[(size_t)row * Cv + tid] = (v - meansh) * rstdsh * g[tid] + bta[tid];
}

// ---------------------------------------------------------------------------
extern "C" void kernel_launch(void* const* d_in, const int* in_sizes, int n_in,
                              void* d_out, int out_size, void* d_ws, size_t ws_size,
                              hipStream_t stream) {
    const float* tgt       = (const float*)d_in[0];
    const float* query_pos = (const float*)d_in[1];
    const float* ref_pts   = (const float*)d_in[2];
    const float* src       = (const float*)d_in[3];
    const float* in_w      = (const float*)d_in[4];
    const float* in_b      = (const float*)d_in[5];
    const float* sa_w      = (const float*)d_in[6];
    const float* sa_b      = (const float*)d_in[7];
    const float* off_w     = (const float*)d_in[8];
    const float* off_b     = (const float*)d_in[9];
    const float* aw_w      = (const float*)d_in[10];
    const float* aw_b      = (const float*)d_in[11];
    const float* val_w     = (const float*)d_in[12];
    const float* val_b     = (const float*)d_in[13];
    const float* co_w      = (const float*)d_in[14];
    const float* co_b      = (const float*)d_in[15];
    const float* ln1_g     = (const float*)d_in[16];
    const float* ln1_b     = (const float*)d_in[17];
    const float* ln2_g     = (const float*)d_in[18];
    const float* ln2_b     = (const float*)d_in[19];
    const float* ln3_g     = (const float*)d_in[20];
    const float* ln3_b     = (const float*)d_in[21];
    const float* f1_w      = (const float*)d_in[22];
    const float* f1_b      = (const float*)d_in[23];
    const float* f2_w      = (const float*)d_in[24];
    const float* f2_b      = (const float*)d_in[25];

    const int M0  = Bv * LQv * Cv;          // 1048576
    const int VSZ = Bv * LSRCv * Cv;        // 22282240
    float* ws = (float*)d_ws;

    // Phase-A buffers alias the (later) bf16 value region — lifetimes disjoint.
    float* big    = ws;                     // VSZ floats
    float* qkbuf  = big;                    // [4096][512]: q cols 0-255, k 256-511
    float* vb     = big + (size_t)2 * M0;
    float* ob     = big + (size_t)3 * M0;
    unsigned short* value16 = (unsigned short*)big;   // VSZ ushorts (phase B)
    float* tgt_a  = ws + (size_t)VSZ;
    float* offs   = tgt_a + M0;
    float* awb    = offs + M0;              // B*LQ*128
    float* sampled= awb + (size_t)Bv * LQv * 128;
    float* tgt_b  = sampled + M0;
    float* hidden = tgt_b + M0;             // B*LQ*DFF
    float* tmp    = hidden + (size_t)Bv * LQv * DFFv;

    const int Mq = Bv * LQv;                // 4096 rows
    dim3 blk256(256);

    // 1. fused q+k projection: A = tgt + query_pos, W = in_w rows 0-511
    gemm_mfma<<<dim3(512 / 128, Mq / 128), blk256, 0, stream>>>(
        tgt, query_pos, in_w, in_b, qkbuf, nullptr, Mq, 512, Cv, 0);
    // 2. v projection
    gemm_mfma<<<dim3(Cv / 128, Mq / 128), blk256, 0, stream>>>(
        tgt, nullptr, in_w + (size_t)2 * Cv * Cv, in_b + 2 * Cv, vb, nullptr, Mq, Cv, Cv, 0);

    // 3. self-attention (MFMA flash; Q/K strided in qkbuf)
    attn_mfma<<<dim3(LQv / 64, Hv, Bv), blk256, 0, stream>>>(qkbuf, qkbuf + 256, vb, ob, 512);

    // 4. output projection, 5. LN2 residual
    gemm_mfma<<<dim3(Cv / 128, Mq / 128), blk256, 0, stream>>>(
        ob, nullptr, sa_w, sa_b, tmp, nullptr, Mq, Cv, Cv, 0);
    ln_residual<<<dim3(Mq), blk256, 0, stream>>>(tgt, tmp, ln2_g, ln2_b, tgt_a);

    // 6. value projection (big GEMM) -> bf16
    gemm_mfma<<<dim3(Cv / 128, (Bv * LSRCv) / 128), blk256, 0, stream>>>(
        src, nullptr, val_w, val_b, nullptr, value16, Bv * LSRCv, Cv, Cv, 0);

    // 7. offsets + aw logits (fused add A = tgt_a + query_pos)
    gemm_mfma<<<dim3(Cv / 128, Mq / 128), blk256, 0, stream>>>(
        tgt_a, query_pos, off_w, off_b, offs, nullptr, Mq, Cv, Cv, 0);
    gemm_mfma<<<dim3(128 / 128, Mq / 128), blk256, 0, stream>>>(
        tgt_a, query_pos, aw_w, aw_b, awb, nullptr, Mq, 128, Cv, 0);

    // 8. deformable bilinear sampling (bf16 value)
    deform_sample<<<dim3(Bv * LQv), blk256, 0, stream>>>(value16, offs, awb, ref_pts, sampled);

    // 9. cross-attn output projection, LN1 residual
    gemm_mfma<<<dim3(Cv / 128, Mq / 128), blk256, 0, stream>>>(
        sampled, nullptr, co_w, co_b, tmp, nullptr, Mq, Cv, Cv, 0);
    ln_residual<<<dim3(Mq), blk256, 0, stream>>>(tgt_a, tmp, ln1_g, ln1_b, tgt_b);

    // 10. FFN + LN3 -> d_out
    gemm_mfma<<<dim3(DFFv / 128, Mq / 128), blk256, 0, stream>>>(
        tgt_b, nullptr, f1_w, f1_b, hidden, nullptr, Mq, DFFv, Cv, 1);
    gemm_mfma<<<dim3(Cv / 128, Mq / 128), blk256, 0, stream>>>(
        hidden, nullptr, f2_w, f2_b, tmp, nullptr, Mq, Cv, DFFv, 0);
    ln_residual<<<dim3(Mq), blk256, 0, stream>>>(tgt_b, tmp, ln3_g, ln3_b, (float*)d_out);
}